// Round 7
// baseline (579.384 us; speedup 1.0000x reference)
//
#include <hip/hip_runtime.h>
#include <cstdint>
#include <cstddef>

// Problem shape (fixed by setup_inputs): B=8, S=2048, D=512. All tensors f32.
#define BATCH 8
#define SEQ   2048
#define DDIM  512
#define NROW  (BATCH*SEQ)          // 16384 token rows
#define KPACK (DDIM/4)             // 128 packed int32 per row
#define EPSQ  1e-5f
#define FSCALE 0.35355339059327373f  // 8 ** -0.5

typedef _Float16 half8 __attribute__((ext_vector_type(8)));
typedef _Float16 half4 __attribute__((ext_vector_type(4)));
typedef float    f32x4 __attribute__((ext_vector_type(4)));

// Workspace layout (bytes)
static constexpr size_t OFF_M   = 0;                                   // 3 floats abs-sum
static constexpr size_t OFF_WP  = 256;                                 // 3*128*512 int32
static constexpr size_t OFF_XQ  = OFF_WP + (size_t)3*KPACK*DDIM*4;     // 16384*128 int32
static constexpr size_t OFF_SX  = OFF_XQ + (size_t)NROW*KPACK*4;       // 16384 f32
static constexpr size_t OFF_QKV = OFF_SX + (size_t)NROW*4;             // 3*16384*512 f16

#if __has_builtin(__builtin_amdgcn_sdot4)
__device__ __forceinline__ int dot4(int a, int b, int c) {
  return __builtin_amdgcn_sdot4(a, b, c, false);
}
#else
__device__ __forceinline__ int dot4(int a, int b, int c) {
  return c + (int)(signed char)(a & 0xff)        * (int)(signed char)(b & 0xff)
           + (int)(signed char)((a >> 8) & 0xff) * (int)(signed char)((b >> 8) & 0xff)
           + (int)(signed char)((a >> 16) & 0xff)* (int)(signed char)((b >> 16) & 0xff)
           + (int)(signed char)(a >> 24)         * (int)(signed char)(b >> 24);
}
#endif

__device__ __forceinline__ int q8(float v, float s) {
  int i = (int)rintf(v * s);
  i = i < -128 ? -128 : (i > 127 ? 127 : i);
  return i & 0xff;
}

// async global->LDS DMA, 16B per lane; lds dest = wave-uniform base + lane*16
__device__ __forceinline__ void gld_lds16(const _Float16* g, _Float16* l) {
  __builtin_amdgcn_global_load_lds(
      (const __attribute__((address_space(1))) void*)g,
      (__attribute__((address_space(3))) void*)l, 16, 0, 0);
}

// ---------------------------------------------------------------------------
// 1. abs-sum of each weight matrix. grid (32,3), block 256; mw pre-zeroed.
// ---------------------------------------------------------------------------
__global__ __launch_bounds__(256) void wsum_kernel(
    const float* __restrict__ Wq, const float* __restrict__ Wk,
    const float* __restrict__ Wv, float* __restrict__ mw) {
  const float* W = blockIdx.y == 0 ? Wq : (blockIdx.y == 1 ? Wk : Wv);
  __shared__ float red[256];
  const float4* p = (const float4*)(W + blockIdx.x * 8192);
  float s = 0.f;
  #pragma unroll
  for (int i = 0; i < 8; i++) {
    float4 a = p[i * 256 + threadIdx.x];
    s += fabsf(a.x) + fabsf(a.y) + fabsf(a.z) + fabsf(a.w);
  }
  red[threadIdx.x] = s;
  __syncthreads();
  for (int w = 128; w > 0; w >>= 1) {
    if ((int)threadIdx.x < w) red[threadIdx.x] += red[threadIdx.x + w];
    __syncthreads();
  }
  if (threadIdx.x == 0) atomicAdd(&mw[blockIdx.y], red[0]);
}

// ---------------------------------------------------------------------------
// 2. ternary-quantize weights, packed K-major: wp[mat][k4][o]. grid 768x256.
// ---------------------------------------------------------------------------
__global__ __launch_bounds__(256) void wquant_kernel(
    const float* __restrict__ Wq, const float* __restrict__ Wk,
    const float* __restrict__ Wv, const float* __restrict__ mw,
    int* __restrict__ wp) {
  int idx = blockIdx.x * 256 + threadIdx.x;   // 0 .. 196607
  int mat = idx >> 16;
  int local = idx & 0xFFFF;
  int o  = local >> 7;       // 0..511
  int k4 = local & 127;      // 0..127
  const float* W = mat == 0 ? Wq : (mat == 1 ? Wk : Wv);
  float mean = mw[mat] * (1.0f / 262144.0f);
  float scale = 1.0f / fmaxf(mean, EPSQ);
  float4 w4 = *(const float4*)(W + (size_t)o * DDIM + k4 * 4);
  int t0 = (int)rintf(w4.x * scale); t0 = t0 < -1 ? -1 : (t0 > 1 ? 1 : t0);
  int t1 = (int)rintf(w4.y * scale); t1 = t1 < -1 ? -1 : (t1 > 1 ? 1 : t1);
  int t2 = (int)rintf(w4.z * scale); t2 = t2 < -1 ? -1 : (t2 > 1 ? 1 : t2);
  int t3 = (int)rintf(w4.w * scale); t3 = t3 < -1 ? -1 : (t3 > 1 ? 1 : t3);
  int packed = (t0 & 0xff) | ((t1 & 0xff) << 8) | ((t2 & 0xff) << 16) | ((t3 & 0xff) << 24);
  wp[(size_t)mat * KPACK * DDIM + (size_t)k4 * DDIM + o] = packed;
}

// ---------------------------------------------------------------------------
// 3. per-token int8 absmax quantization. One wave per 512-elem row.
// ---------------------------------------------------------------------------
__global__ __launch_bounds__(256) void aquant_kernel(
    const float* __restrict__ x, int* __restrict__ xq, float* __restrict__ sx) {
  int wid = threadIdx.x >> 6, lane = threadIdx.x & 63;
  int row = blockIdx.x * 4 + wid;
  const float* xr = x + (size_t)row * DDIM;
  float4 a = ((const float4*)xr)[lane];        // k = 4*lane .. +3
  float4 b = ((const float4*)xr)[64 + lane];   // k = 256+4*lane .. +3
  float amax = fmaxf(fmaxf(fmaxf(fabsf(a.x), fabsf(a.y)), fmaxf(fabsf(a.z), fabsf(a.w))),
                     fmaxf(fmaxf(fabsf(b.x), fabsf(b.y)), fmaxf(fabsf(b.z), fabsf(b.w))));
  for (int off = 32; off > 0; off >>= 1) amax = fmaxf(amax, __shfl_xor(amax, off, 64));
  float aa = fmaxf(amax, EPSQ);
  float scale = 127.0f / aa;
  int p0 = q8(a.x, scale) | (q8(a.y, scale) << 8) | (q8(a.z, scale) << 16) | (q8(a.w, scale) << 24);
  int p1 = q8(b.x, scale) | (q8(b.y, scale) << 8) | (q8(b.z, scale) << 16) | (q8(b.w, scale) << 24);
  xq[(size_t)row * KPACK + lane]      = p0;    // k4 = lane
  xq[(size_t)row * KPACK + 64 + lane] = p1;    // k4 = 64+lane
  if (lane == 0) sx[row] = aa * (1.0f / 127.0f);
}

// ---------------------------------------------------------------------------
// 4. int8 x ternary GEMM -> f16. grid (1024, 4, 3), block 256.
//    mats 0,1 (Q,K): natural [row][dim]. mat 2 (V): tiled-transposed
//    vT[b][kt=srow>>5][dim][srow&31] so each flash V-tile is contiguous 32 KB.
// ---------------------------------------------------------------------------
__global__ __launch_bounds__(256) void qkv_gemm_kernel(
    const int* __restrict__ xq, const int* __restrict__ wp,
    const float* __restrict__ sx, const float* __restrict__ mw,
    _Float16* __restrict__ qkv) {
  __shared__ int xs[16][KPACK];
  int tid = threadIdx.x;
  int r0  = blockIdx.x * 16;
  int ocl = tid & 127;
  int rg  = tid >> 7;
  int oc  = blockIdx.y * 128 + ocl;
  int mat = blockIdx.z;

  #pragma unroll
  for (int i = 0; i < 8; i++) {
    int e = i * 256 + tid;
    ((int*)xs)[e] = xq[(size_t)r0 * KPACK + e];
  }
  __syncthreads();

  const int* wcol = wp + (size_t)mat * KPACK * DDIM + oc;
  int acc[8] = {0, 0, 0, 0, 0, 0, 0, 0};
  #pragma unroll 4
  for (int k4 = 0; k4 < KPACK; k4++) {
    int wv = wcol[(size_t)k4 * DDIM];
    #pragma unroll
    for (int rr = 0; rr < 8; rr++)
      acc[rr] = dot4(xs[rg * 8 + rr][k4], wv, acc[rr]);
  }
  float mval = fmaxf(mw[mat] * (1.0f / 262144.0f), EPSQ);
  if (mat < 2) {
    _Float16* outb = qkv + (size_t)mat * NROW * DDIM;
    #pragma unroll
    for (int rr = 0; rr < 8; rr++) {
      int row = r0 + rg * 8 + rr;
      outb[(size_t)row * DDIM + oc] = (_Float16)((float)acc[rr] * sx[row] * mval);
    }
  } else {
    _Float16* vT = qkv + (size_t)2 * NROW * DDIM;
    int b = r0 >> 11;                    // rows r0..r0+15 in one batch (16 | 2048)
    int srow0 = (r0 & 2047) + rg * 8;    // 8 consecutive keys, same 32-block
    int kt = srow0 >> 5, kin = srow0 & 31;
    half8 hv;
    #pragma unroll
    for (int rr = 0; rr < 8; rr++) {
      int row = r0 + rg * 8 + rr;
      hv[rr] = (_Float16)((float)acc[rr] * sx[row] * mval);
    }
    *(half8*)(vT + ((((size_t)b * 64 + kt) * 512 + oc) * 32 + kin)) = hv;
  }
}

// ---------------------------------------------------------------------------
// 5. f16 MFMA flash attention, causal, scale 8^-0.5.
//    512 thr = 8 waves, BM=64, BN=32, grid (32,8), 2 complementary phases.
//    K: streamed from global into registers (L1-cached; no LDS). V^T: async
//    DMA double-buffer with XOR bank swizzle (unit u of dim-row r holds global
//    key-chunk u ^ ((r>>1)&3); 2-way banks = free). P: f32/f16 aliased,
//    stride 72 halfs (16B-aligned rows). MFMA layouts as r4-r6 (verified).
// ---------------------------------------------------------------------------
__global__ __launch_bounds__(512, 2) void flash_kernel(
    const _Float16* __restrict__ q, const _Float16* __restrict__ k,
    const _Float16* __restrict__ vT, float* __restrict__ out) {
  __shared__ __align__(16) _Float16 VtL[2][512][32];  // 65,536 B (DMA, swizzled)
  __shared__ __align__(16) float    PsU[64 * 36];     // 9,216 B; alias Pf stride 72
  __shared__ float alpha_l[64];
  __shared__ float invl_l[64];

  const int tid  = threadIdx.x;
  const int w    = tid >> 6;        // 0..7
  const int lane = tid & 63;
  const int quad = lane >> 4;
  const int col  = lane & 15;
  const int rt   = w & 3;           // score row-tile
  const int kh   = w >> 2;          // score key-half
  const int smrow = tid >> 3;       // softmax row 0..63
  const int sme   = tid & 7;        // softmax key group 0..7
  const int d0  = w * 64;           // PV dim slice
  _Float16* Pf = (_Float16*)PsU;

  // V-DMA lane map: 16 dim-rows x 4 units per gld group
  const int vrl = lane >> 2;        // row-in-group 0..15
  const int vu  = lane & 3;         // 16B unit 0..3

  const int qi = blockIdx.x, batch = blockIdx.y;

  for (int ph = 0; ph < 2; ph++) {
    const int qt = ph ? (31 - qi) : qi;
    const int bb = ph ? (batch ^ 1) : batch;
    const int qrow0 = qt * 64;
    const size_t bbase = (size_t)bb * SEQ * DDIM;
    const _Float16* kb_p = k + bbase;
    const _Float16* vt_p = vT + (size_t)bb * 64 * 512 * 32;  // [kt][dim][key]

    // Q A-frags in registers (rows qrow0 + rt*16 + col)
    half8 qfrag[16];
    {
      const _Float16* qrow_p = q + bbase + (size_t)(qrow0 + rt * 16 + col) * DDIM;
      #pragma unroll
      for (int s = 0; s < 16; s++)
        qfrag[s] = *(const half8*)(qrow_p + s * 32 + quad * 8);
    }

    float m_run = -INFINITY, l_run = 0.f;
    f32x4 o[4][4];
    #pragma unroll
    for (int a = 0; a < 4; a++)
      #pragma unroll
      for (int b = 0; b < 4; b++) o[a][b] = (f32x4)(0.f);

    const int ntiles = 2 * (qt + 1);

    // prologue: DMA V tile 0 (swizzled) + load K frags for tile 0
    #pragma unroll
    for (int i = 0; i < 4; i++) {
      int r = w * 64 + i * 16 + vrl;
      int su = vu ^ ((r >> 1) & 3);
      gld_lds16(vt_p + (size_t)r * 32 + su * 8, &VtL[0][w * 64 + i * 16][0]);
    }
    half8 kf[16];
    {
      const _Float16* kp0 = kb_p + (size_t)(kh * 16 + col) * DDIM + quad * 8;
      #pragma unroll
      for (int s = 0; s < 16; s++) kf[s] = *(const half8*)(kp0 + s * 32);
    }
    __syncthreads();

    for (int kt = 0; kt < ntiles; kt++) {
      const int cur = kt & 1, nxt = cur ^ 1;
      const int kb0 = kt * 32;

      // V-DMA prefetch tile kt+1 (drains at B, covered by scores)
      if (kt + 1 < ntiles) {
        const _Float16* vtile = vt_p + (size_t)(kt + 1) * 512 * 32;
        #pragma unroll
        for (int i = 0; i < 4; i++) {
          int r = w * 64 + i * 16 + vrl;
          int su = vu ^ ((r >> 1) & 3);
          gld_lds16(vtile + (size_t)r * 32 + su * 8, &VtL[nxt][w * 64 + i * 16][0]);
        }
      }

      // ---- scores: wave (rt,kh): rows rt*16..+15 x keys kb0+kh*16..+15 ----
      {
        f32x4 c = (f32x4)(0.f);
        #pragma unroll
        for (int s = 0; s < 16; s++)
          c = __builtin_amdgcn_mfma_f32_16x16x32_f16(qfrag[s], kf[s], c, 0, 0, 0);
        #pragma unroll
        for (int reg = 0; reg < 4; reg++)
          PsU[(rt * 16 + quad * 4 + reg) * 36 + kh * 16 + col] = c[reg];
      }
      __syncthreads();   // B: scores ready (drains V-DMA)

      // prefetch K frags for tile kt+1 (kf dead after scores; drains at C,
      // hidden behind softmax; consumed a full phase later)
      if (kt + 1 < ntiles) {
        const _Float16* kp2 = kb_p + (size_t)(kb0 + 32 + kh * 16 + col) * DDIM + quad * 8;
        #pragma unroll
        for (int s = 0; s < 16; s++) kf[s] = *(const half8*)(kp2 + s * 32);
      }

      // ---- softmax: thread (smrow, sme) handles keys sme*4..+3 ----
      {
        const int qrow = qrow0 + smrow;
        float sv[4];
        #pragma unroll
        for (int i = 0; i < 4; i++) {
          float s = PsU[smrow * 36 + sme * 4 + i] * FSCALE;
          if (kb0 + sme * 4 + i > qrow) s = -INFINITY;
          sv[i] = s;
        }
        float mx = fmaxf(fmaxf(sv[0], sv[1]), fmaxf(sv[2], sv[3]));
        #pragma unroll
        for (int m = 1; m <= 4; m <<= 1) mx = fmaxf(mx, __shfl_xor(mx, m, 64));
        float mn = fmaxf(m_run, mx);
        float al = __expf(m_run - mn);
        half4 p4;
        float rs = 0.f;
        #pragma unroll
        for (int i = 0; i < 4; i++) {
          float p = __expf(sv[i] - mn);
          rs += p;
          p4[i] = (_Float16)p;
        }
        #pragma unroll
        for (int m = 1; m <= 4; m <<= 1) rs += __shfl_xor(rs, m, 64);
        l_run = l_run * al + rs;
        m_run = mn;
        // aliased write: same-row/same-wave containment => no race
        *(half4*)&Pf[smrow * 72 + sme * 4] = p4;
        if (sme == 0) alpha_l[smrow] = al;
      }
      __syncthreads();   // C: Pf16 + alpha ready (drains kf prefetch)

      // ---- PV: wave w owns dims d0..d0+63 for all 64 rows ----
      {
        half8 ap[4];
        f32x4 af[4];
        #pragma unroll
        for (int r2 = 0; r2 < 4; r2++) {
          ap[r2] = *(const half8*)&Pf[(r2 * 16 + col) * 72 + quad * 8];
          af[r2] = *(const f32x4*)&alpha_l[r2 * 16 + quad * 4];
        }
        #pragma unroll
        for (int r2 = 0; r2 < 4; r2++)
          #pragma unroll
          for (int ct = 0; ct < 4; ct++)
            o[r2][ct] *= af[r2];
        #pragma unroll
        for (int ct = 0; ct < 4; ct++) {
          int R = d0 + ct * 16 + col;
          int ur = quad ^ ((R >> 1) & 3);
          half8 bv = *(const half8*)&VtL[cur][R][ur * 8];
          #pragma unroll
          for (int r2 = 0; r2 < 4; r2++)
            o[r2][ct] = __builtin_amdgcn_mfma_f32_16x16x32_f16(ap[r2], bv, o[r2][ct], 0, 0, 0);
        }
      }
      __syncthreads();   // D: PV done; VtL[cur] may be re-DMA'd next iter
    }

    // ---- finalize ----
    if (sme == 0) invl_l[smrow] = 1.0f / l_run;
    __syncthreads();
    #pragma unroll
    for (int r2 = 0; r2 < 4; r2++) {
      f32x4 iv = *(const f32x4*)&invl_l[r2 * 16 + quad * 4];
      #pragma unroll
      for (int ct = 0; ct < 4; ct++) {
        #pragma unroll
        for (int e = 0; e < 4; e++) {
          out[((size_t)bb * SEQ + qrow0 + r2 * 16 + quad * 4 + e) * DDIM
              + d0 + ct * 16 + col] = o[r2][ct][e] * iv[e];
        }
      }
    }
    __syncthreads();   // protect LDS before next phase's prologue
  }
}

// ---------------------------------------------------------------------------
extern "C" void kernel_launch(void* const* d_in, const int* in_sizes, int n_in,
                              void* d_out, int out_size, void* d_ws, size_t ws_size,
                              hipStream_t stream) {
  const float* x  = (const float*)d_in[0];
  const float* Wq = (const float*)d_in[1];
  const float* Wk = (const float*)d_in[2];
  const float* Wv = (const float*)d_in[3];
  float* out = (float*)d_out;
  char* ws = (char*)d_ws;

  float* mw  = (float*)(ws + OFF_M);
  int*   wp  = (int*)(ws + OFF_WP);
  int*   xq  = (int*)(ws + OFF_XQ);
  float* sx  = (float*)(ws + OFF_SX);
  _Float16* qkv = (_Float16*)(ws + OFF_QKV);
  _Float16* qf  = qkv;
  _Float16* kf  = qkv + (size_t)NROW * DDIM;
  _Float16* vTf = qkv + 2 * (size_t)NROW * DDIM;

  hipMemsetAsync(mw, 0, 16, stream);
  wsum_kernel<<<dim3(32, 3), 256, 0, stream>>>(Wq, Wk, Wv, mw);
  wquant_kernel<<<768, 256, 0, stream>>>(Wq, Wk, Wv, mw, wp);
  aquant_kernel<<<4096, 256, 0, stream>>>(x, xq, sx);
  qkv_gemm_kernel<<<dim3(1024, 4, 3), 256, 0, stream>>>(xq, wp, sx, mw, qkv);
  flash_kernel<<<dim3(32, 8), 512, 0, stream>>>(qf, kf, vTf, out);
}

// Round 8
// 378.139 us; speedup vs baseline: 1.5322x; 1.5322x over previous
//
#include <hip/hip_runtime.h>
#include <cstdint>
#include <cstddef>

// Problem shape (fixed by setup_inputs): B=8, S=2048, D=512. All tensors f32.
#define BATCH 8
#define SEQ   2048
#define DDIM  512
#define NROW  (BATCH*SEQ)          // 16384 token rows
#define KPACK (DDIM/4)             // 128 packed int32 per row
#define EPSQ  1e-5f
#define FSCALE 0.35355339059327373f  // 8 ** -0.5

typedef _Float16 half8 __attribute__((ext_vector_type(8)));
typedef _Float16 half4 __attribute__((ext_vector_type(4)));
typedef float    f32x4 __attribute__((ext_vector_type(4)));

// Workspace layout (bytes)
static constexpr size_t OFF_M   = 0;                                   // 3 floats abs-sum
static constexpr size_t OFF_WP  = 256;                                 // 3*128*512 int32
static constexpr size_t OFF_XQ  = OFF_WP + (size_t)3*KPACK*DDIM*4;     // 16384*128 int32
static constexpr size_t OFF_SX  = OFF_XQ + (size_t)NROW*KPACK*4;       // 16384 f32
static constexpr size_t OFF_QKV = OFF_SX + (size_t)NROW*4;             // 3*16384*512 f16

#if __has_builtin(__builtin_amdgcn_sdot4)
__device__ __forceinline__ int dot4(int a, int b, int c) {
  return __builtin_amdgcn_sdot4(a, b, c, false);
}
#else
__device__ __forceinline__ int dot4(int a, int b, int c) {
  return c + (int)(signed char)(a & 0xff)        * (int)(signed char)(b & 0xff)
           + (int)(signed char)((a >> 8) & 0xff) * (int)(signed char)((b >> 8) & 0xff)
           + (int)(signed char)((a >> 16) & 0xff)* (int)(signed char)((b >> 16) & 0xff)
           + (int)(signed char)(a >> 24)         * (int)(signed char)(b >> 24);
}
#endif

__device__ __forceinline__ int q8(float v, float s) {
  int i = (int)rintf(v * s);
  i = i < -128 ? -128 : (i > 127 ? 127 : i);
  return i & 0xff;
}

// async global->LDS DMA, 16B per lane; lds dest = wave-uniform base + lane*16
__device__ __forceinline__ void gld_lds16(const _Float16* g, _Float16* l) {
  __builtin_amdgcn_global_load_lds(
      (const __attribute__((address_space(1))) void*)g,
      (__attribute__((address_space(3))) void*)l, 16, 0, 0);
}

// ---------------------------------------------------------------------------
// 1. abs-sum of each weight matrix. grid (32,3), block 256; mw pre-zeroed.
// ---------------------------------------------------------------------------
__global__ __launch_bounds__(256) void wsum_kernel(
    const float* __restrict__ Wq, const float* __restrict__ Wk,
    const float* __restrict__ Wv, float* __restrict__ mw) {
  const float* W = blockIdx.y == 0 ? Wq : (blockIdx.y == 1 ? Wk : Wv);
  __shared__ float red[256];
  const float4* p = (const float4*)(W + blockIdx.x * 8192);
  float s = 0.f;
  #pragma unroll
  for (int i = 0; i < 8; i++) {
    float4 a = p[i * 256 + threadIdx.x];
    s += fabsf(a.x) + fabsf(a.y) + fabsf(a.z) + fabsf(a.w);
  }
  red[threadIdx.x] = s;
  __syncthreads();
  for (int w = 128; w > 0; w >>= 1) {
    if ((int)threadIdx.x < w) red[threadIdx.x] += red[threadIdx.x + w];
    __syncthreads();
  }
  if (threadIdx.x == 0) atomicAdd(&mw[blockIdx.y], red[0]);
}

// ---------------------------------------------------------------------------
// 2. ternary-quantize weights, packed K-major: wp[mat][k4][o]. grid 768x256.
// ---------------------------------------------------------------------------
__global__ __launch_bounds__(256) void wquant_kernel(
    const float* __restrict__ Wq, const float* __restrict__ Wk,
    const float* __restrict__ Wv, const float* __restrict__ mw,
    int* __restrict__ wp) {
  int idx = blockIdx.x * 256 + threadIdx.x;   // 0 .. 196607
  int mat = idx >> 16;
  int local = idx & 0xFFFF;
  int o  = local >> 7;       // 0..511
  int k4 = local & 127;      // 0..127
  const float* W = mat == 0 ? Wq : (mat == 1 ? Wk : Wv);
  float mean = mw[mat] * (1.0f / 262144.0f);
  float scale = 1.0f / fmaxf(mean, EPSQ);
  float4 w4 = *(const float4*)(W + (size_t)o * DDIM + k4 * 4);
  int t0 = (int)rintf(w4.x * scale); t0 = t0 < -1 ? -1 : (t0 > 1 ? 1 : t0);
  int t1 = (int)rintf(w4.y * scale); t1 = t1 < -1 ? -1 : (t1 > 1 ? 1 : t1);
  int t2 = (int)rintf(w4.z * scale); t2 = t2 < -1 ? -1 : (t2 > 1 ? 1 : t2);
  int t3 = (int)rintf(w4.w * scale); t3 = t3 < -1 ? -1 : (t3 > 1 ? 1 : t3);
  int packed = (t0 & 0xff) | ((t1 & 0xff) << 8) | ((t2 & 0xff) << 16) | ((t3 & 0xff) << 24);
  wp[(size_t)mat * KPACK * DDIM + (size_t)k4 * DDIM + o] = packed;
}

// ---------------------------------------------------------------------------
// 3. per-token int8 absmax quantization. One wave per 512-elem row.
// ---------------------------------------------------------------------------
__global__ __launch_bounds__(256) void aquant_kernel(
    const float* __restrict__ x, int* __restrict__ xq, float* __restrict__ sx) {
  int wid = threadIdx.x >> 6, lane = threadIdx.x & 63;
  int row = blockIdx.x * 4 + wid;
  const float* xr = x + (size_t)row * DDIM;
  float4 a = ((const float4*)xr)[lane];        // k = 4*lane .. +3
  float4 b = ((const float4*)xr)[64 + lane];   // k = 256+4*lane .. +3
  float amax = fmaxf(fmaxf(fmaxf(fabsf(a.x), fabsf(a.y)), fmaxf(fabsf(a.z), fabsf(a.w))),
                     fmaxf(fmaxf(fabsf(b.x), fabsf(b.y)), fmaxf(fabsf(b.z), fabsf(b.w))));
  for (int off = 32; off > 0; off >>= 1) amax = fmaxf(amax, __shfl_xor(amax, off, 64));
  float aa = fmaxf(amax, EPSQ);
  float scale = 127.0f / aa;
  int p0 = q8(a.x, scale) | (q8(a.y, scale) << 8) | (q8(a.z, scale) << 16) | (q8(a.w, scale) << 24);
  int p1 = q8(b.x, scale) | (q8(b.y, scale) << 8) | (q8(b.z, scale) << 16) | (q8(b.w, scale) << 24);
  xq[(size_t)row * KPACK + lane]      = p0;    // k4 = lane
  xq[(size_t)row * KPACK + 64 + lane] = p1;    // k4 = 64+lane
  if (lane == 0) sx[row] = aa * (1.0f / 127.0f);
}

// ---------------------------------------------------------------------------
// 4. int8 x ternary GEMM -> f16. grid (1024, 4, 3), block 256.
//    mats 0,1 (Q,K): natural [row][dim]. mat 2 (V): tiled-transposed
//    vT[b][kt=srow>>5][dim][srow&31] so each flash V-tile is contiguous 32 KB.
// ---------------------------------------------------------------------------
__global__ __launch_bounds__(256) void qkv_gemm_kernel(
    const int* __restrict__ xq, const int* __restrict__ wp,
    const float* __restrict__ sx, const float* __restrict__ mw,
    _Float16* __restrict__ qkv) {
  __shared__ int xs[16][KPACK];
  int tid = threadIdx.x;
  int r0  = blockIdx.x * 16;
  int ocl = tid & 127;
  int rg  = tid >> 7;
  int oc  = blockIdx.y * 128 + ocl;
  int mat = blockIdx.z;

  #pragma unroll
  for (int i = 0; i < 8; i++) {
    int e = i * 256 + tid;
    ((int*)xs)[e] = xq[(size_t)r0 * KPACK + e];
  }
  __syncthreads();

  const int* wcol = wp + (size_t)mat * KPACK * DDIM + oc;
  int acc[8] = {0, 0, 0, 0, 0, 0, 0, 0};
  #pragma unroll 4
  for (int k4 = 0; k4 < KPACK; k4++) {
    int wv = wcol[(size_t)k4 * DDIM];
    #pragma unroll
    for (int rr = 0; rr < 8; rr++)
      acc[rr] = dot4(xs[rg * 8 + rr][k4], wv, acc[rr]);
  }
  float mval = fmaxf(mw[mat] * (1.0f / 262144.0f), EPSQ);
  if (mat < 2) {
    _Float16* outb = qkv + (size_t)mat * NROW * DDIM;
    #pragma unroll
    for (int rr = 0; rr < 8; rr++) {
      int row = r0 + rg * 8 + rr;
      outb[(size_t)row * DDIM + oc] = (_Float16)((float)acc[rr] * sx[row] * mval);
    }
  } else {
    _Float16* vT = qkv + (size_t)2 * NROW * DDIM;
    int b = r0 >> 11;                    // rows r0..r0+15 in one batch (16 | 2048)
    int srow0 = (r0 & 2047) + rg * 8;    // 8 consecutive keys, same 32-block
    int kt = srow0 >> 5, kin = srow0 & 31;
    half8 hv;
    #pragma unroll
    for (int rr = 0; rr < 8; rr++) {
      int row = r0 + rg * 8 + rr;
      hv[rr] = (_Float16)((float)acc[rr] * sx[row] * mval);
    }
    *(half8*)(vT + ((((size_t)b * 64 + kt) * 512 + oc) * 32 + kin)) = hv;
  }
}

// ---------------------------------------------------------------------------
// 5. f16 MFMA flash attention, causal, scale 8^-0.5.
//    512 thr = 8 waves, BM=64, BN=32, grid (32,8), 2 complementary phases.
//    K: async DMA double-buffer (r6 structure). V^T: async DMA double-buffer
//    with XOR bank swizzle (r7-proven). P split: PsS f32 stride 33 (softmax
//    reads conflict-free), Pf f16 stride 40 (b128-aligned ap reads, 2-way).
//    MFMA layouts as r4-r7 (bench-verified).
// ---------------------------------------------------------------------------
__global__ __launch_bounds__(512, 2) void flash_kernel(
    const _Float16* __restrict__ q, const _Float16* __restrict__ k,
    const _Float16* __restrict__ vT, float* __restrict__ out) {
  __shared__ __align__(16) _Float16 Ksh[2][32][520];  // 66,560 B (DMA rows)
  __shared__ __align__(16) _Float16 VtL[2][512][32];  // 65,536 B (DMA, swizzled)
  __shared__ __align__(16) float    PsS[64 * 33];     // 8,448 B raw scores
  __shared__ __align__(16) _Float16 Pf[64 * 40];      // 5,120 B probabilities
  __shared__ float alpha_l[64];
  __shared__ float invl_l[64];

  const int tid  = threadIdx.x;
  const int w    = tid >> 6;        // 0..7
  const int lane = tid & 63;
  const int quad = lane >> 4;
  const int col  = lane & 15;
  const int rt   = w & 3;           // score row-tile
  const int kh   = w >> 2;          // score key-half
  const int smrow = tid >> 3;       // softmax row 0..63
  const int sme   = tid & 7;        // softmax key group 0..7
  const int d0  = w * 64;           // PV dim slice

  // V-DMA lane map: 16 dim-rows x 4 units per gld group
  const int vrl = lane >> 2;        // row-in-group 0..15
  const int vu  = lane & 3;         // 16B unit 0..3

  const int qi = blockIdx.x, batch = blockIdx.y;

  for (int ph = 0; ph < 2; ph++) {
    const int qt = ph ? (31 - qi) : qi;
    const int bb = ph ? (batch ^ 1) : batch;
    const int qrow0 = qt * 64;
    const size_t bbase = (size_t)bb * SEQ * DDIM;
    const _Float16* kb_p = k + bbase;
    const _Float16* vt_p = vT + (size_t)bb * 64 * 512 * 32;  // [kt][dim][key]

    // Q A-frags in registers (rows qrow0 + rt*16 + col)
    half8 qfrag[16];
    {
      const _Float16* qrow_p = q + bbase + (size_t)(qrow0 + rt * 16 + col) * DDIM;
      #pragma unroll
      for (int s = 0; s < 16; s++)
        qfrag[s] = *(const half8*)(qrow_p + s * 32 + quad * 8);
    }

    float m_run = -INFINITY, l_run = 0.f;
    f32x4 o[4][4];
    #pragma unroll
    for (int a = 0; a < 4; a++)
      #pragma unroll
      for (int b = 0; b < 4; b++) o[a][b] = (f32x4)(0.f);

    const int ntiles = 2 * (qt + 1);

    // prologue: DMA K tile 0 + V tile 0 (swizzled) into buf 0
    #pragma unroll
    for (int i = 0; i < 4; i++)
      gld_lds16(kb_p + (size_t)(w * 4 + i) * DDIM + lane * 8, &Ksh[0][w * 4 + i][0]);
    #pragma unroll
    for (int i = 0; i < 4; i++) {
      int r = w * 64 + i * 16 + vrl;
      int su = vu ^ ((r >> 1) & 3);
      gld_lds16(vt_p + (size_t)r * 32 + su * 8, &VtL[0][w * 64 + i * 16][0]);
    }
    __syncthreads();

    for (int kt = 0; kt < ntiles; kt++) {
      const int cur = kt & 1, nxt = cur ^ 1;
      const int kb0 = kt * 32;

      // prefetch tile kt+1 (drains at barrier B, covered by scores phase)
      if (kt + 1 < ntiles) {
        const int kb1 = kb0 + 32;
        #pragma unroll
        for (int i = 0; i < 4; i++)
          gld_lds16(kb_p + (size_t)(kb1 + w * 4 + i) * DDIM + lane * 8,
                    &Ksh[nxt][w * 4 + i][0]);
        const _Float16* vtile = vt_p + (size_t)(kt + 1) * 512 * 32;
        #pragma unroll
        for (int i = 0; i < 4; i++) {
          int r = w * 64 + i * 16 + vrl;
          int su = vu ^ ((r >> 1) & 3);
          gld_lds16(vtile + (size_t)r * 32 + su * 8, &VtL[nxt][w * 64 + i * 16][0]);
        }
      }

      // ---- scores: wave (rt,kh): rows rt*16..+15 x keys kb0+kh*16..+15 ----
      {
        f32x4 c = (f32x4)(0.f);
        #pragma unroll
        for (int s = 0; s < 16; s++) {
          half8 b = *(const half8*)&Ksh[cur][kh * 16 + col][s * 32 + quad * 8];
          c = __builtin_amdgcn_mfma_f32_16x16x32_f16(qfrag[s], b, c, 0, 0, 0);
        }
        #pragma unroll
        for (int reg = 0; reg < 4; reg++)
          PsS[(rt * 16 + quad * 4 + reg) * 33 + kh * 16 + col] = c[reg];
      }
      __syncthreads();   // B: scores ready (drains DMA prefetch)

      // ---- softmax: thread (smrow, sme) handles keys sme*4..+3 ----
      {
        const int qrow = qrow0 + smrow;
        float sv[4];
        #pragma unroll
        for (int i = 0; i < 4; i++) {
          float s = PsS[smrow * 33 + sme * 4 + i] * FSCALE;
          if (kb0 + sme * 4 + i > qrow) s = -INFINITY;
          sv[i] = s;
        }
        float mx = fmaxf(fmaxf(sv[0], sv[1]), fmaxf(sv[2], sv[3]));
        #pragma unroll
        for (int m = 1; m <= 4; m <<= 1) mx = fmaxf(mx, __shfl_xor(mx, m, 64));
        float mn = fmaxf(m_run, mx);
        float al = __expf(m_run - mn);
        half4 p4;
        float rs = 0.f;
        #pragma unroll
        for (int i = 0; i < 4; i++) {
          float p = __expf(sv[i] - mn);
          rs += p;
          p4[i] = (_Float16)p;
        }
        #pragma unroll
        for (int m = 1; m <= 4; m <<= 1) rs += __shfl_xor(rs, m, 64);
        l_run = l_run * al + rs;
        m_run = mn;
        *(half4*)&Pf[smrow * 40 + sme * 4] = p4;
        if (sme == 0) alpha_l[smrow] = al;
      }
      __syncthreads();   // C: Pf + alpha ready

      // ---- PV: wave w owns dims d0..d0+63 for all 64 rows ----
      {
        half8 ap[4];
        f32x4 af[4];
        #pragma unroll
        for (int r2 = 0; r2 < 4; r2++) {
          ap[r2] = *(const half8*)&Pf[(r2 * 16 + col) * 40 + quad * 8];
          af[r2] = *(const f32x4*)&alpha_l[r2 * 16 + quad * 4];
        }
        #pragma unroll
        for (int r2 = 0; r2 < 4; r2++)
          #pragma unroll
          for (int ct = 0; ct < 4; ct++)
            o[r2][ct] *= af[r2];
        #pragma unroll
        for (int ct = 0; ct < 4; ct++) {
          int R = d0 + ct * 16 + col;
          int ur = quad ^ ((R >> 1) & 3);
          half8 bv = *(const half8*)&VtL[cur][R][ur * 8];
          #pragma unroll
          for (int r2 = 0; r2 < 4; r2++)
            o[r2][ct] = __builtin_amdgcn_mfma_f32_16x16x32_f16(ap[r2], bv, o[r2][ct], 0, 0, 0);
        }
      }
      __syncthreads();   // D: PV done; cur bufs may be re-DMA'd next iter
    }

    // ---- finalize ----
    if (sme == 0) invl_l[smrow] = 1.0f / l_run;
    __syncthreads();
    #pragma unroll
    for (int r2 = 0; r2 < 4; r2++) {
      f32x4 iv = *(const f32x4*)&invl_l[r2 * 16 + quad * 4];
      #pragma unroll
      for (int ct = 0; ct < 4; ct++) {
        #pragma unroll
        for (int e = 0; e < 4; e++) {
          out[((size_t)bb * SEQ + qrow0 + r2 * 16 + quad * 4 + e) * DDIM
              + d0 + ct * 16 + col] = o[r2][ct][e] * iv[e];
        }
      }
    }
    __syncthreads();   // protect LDS before next phase's prologue
  }
}

// ---------------------------------------------------------------------------
extern "C" void kernel_launch(void* const* d_in, const int* in_sizes, int n_in,
                              void* d_out, int out_size, void* d_ws, size_t ws_size,
                              hipStream_t stream) {
  const float* x  = (const float*)d_in[0];
  const float* Wq = (const float*)d_in[1];
  const float* Wk = (const float*)d_in[2];
  const float* Wv = (const float*)d_in[3];
  float* out = (float*)d_out;
  char* ws = (char*)d_ws;

  float* mw  = (float*)(ws + OFF_M);
  int*   wp  = (int*)(ws + OFF_WP);
  int*   xq  = (int*)(ws + OFF_XQ);
  float* sx  = (float*)(ws + OFF_SX);
  _Float16* qkv = (_Float16*)(ws + OFF_QKV);
  _Float16* qf  = qkv;
  _Float16* kf  = qkv + (size_t)NROW * DDIM;
  _Float16* vTf = qkv + 2 * (size_t)NROW * DDIM;

  hipMemsetAsync(mw, 0, 16, stream);
  wsum_kernel<<<dim3(32, 3), 256, 0, stream>>>(Wq, Wk, Wv, mw);
  wquant_kernel<<<768, 256, 0, stream>>>(Wq, Wk, Wv, mw, wp);
  aquant_kernel<<<4096, 256, 0, stream>>>(x, xq, sx);
  qkv_gemm_kernel<<<dim3(1024, 4, 3), 256, 0, stream>>>(xq, wp, sx, mw, qkv);
  flash_kernel<<<dim3(32, 8), 512, 0, stream>>>(qf, kf, vTf, out);
}

// Round 9
// 292.112 us; speedup vs baseline: 1.9834x; 1.2945x over previous
//
#include <hip/hip_runtime.h>
#include <cstdint>
#include <cstddef>

// Problem shape (fixed by setup_inputs): B=8, S=2048, D=512. All tensors f32.
#define BATCH 8
#define SEQ   2048
#define DDIM  512
#define NROW  (BATCH*SEQ)          // 16384 token rows
#define KPACK (DDIM/4)             // 128 packed int32 per row
#define EPSQ  1e-5f
#define FSCALE 0.35355339059327373f  // 8 ** -0.5

typedef _Float16 half8 __attribute__((ext_vector_type(8)));
typedef _Float16 half4 __attribute__((ext_vector_type(4)));
typedef float    f32x4 __attribute__((ext_vector_type(4)));
typedef int      i32x4 __attribute__((ext_vector_type(4)));

// Workspace layout (bytes)
static constexpr size_t OFF_M   = 0;                                   // 3 floats abs-sum
static constexpr size_t OFF_WP  = 256;                                 // 3*512*128 int32 (col-major)
static constexpr size_t OFF_XQ  = OFF_WP + (size_t)3*KPACK*DDIM*4;     // 16384*128 int32
static constexpr size_t OFF_SX  = OFF_XQ + (size_t)NROW*KPACK*4;       // 16384 f32
static constexpr size_t OFF_QKV = OFF_SX + (size_t)NROW*4;             // 3*16384*512 f16

__device__ __forceinline__ int q8(float v, float s) {
  int i = (int)rintf(v * s);
  i = i < -128 ? -128 : (i > 127 ? 127 : i);
  return i & 0xff;
}

// async global->LDS DMA, 16B per lane; lds dest = wave-uniform base + lane*16
__device__ __forceinline__ void gld_lds16(const _Float16* g, _Float16* l) {
  __builtin_amdgcn_global_load_lds(
      (const __attribute__((address_space(1))) void*)g,
      (__attribute__((address_space(3))) void*)l, 16, 0, 0);
}

// ---------------------------------------------------------------------------
// 1. abs-sum of each weight matrix. grid (32,3), block 256; mw pre-zeroed.
// ---------------------------------------------------------------------------
__global__ __launch_bounds__(256) void wsum_kernel(
    const float* __restrict__ Wq, const float* __restrict__ Wk,
    const float* __restrict__ Wv, float* __restrict__ mw) {
  const float* W = blockIdx.y == 0 ? Wq : (blockIdx.y == 1 ? Wk : Wv);
  __shared__ float red[256];
  const float4* p = (const float4*)(W + blockIdx.x * 8192);
  float s = 0.f;
  #pragma unroll
  for (int i = 0; i < 8; i++) {
    float4 a = p[i * 256 + threadIdx.x];
    s += fabsf(a.x) + fabsf(a.y) + fabsf(a.z) + fabsf(a.w);
  }
  red[threadIdx.x] = s;
  __syncthreads();
  for (int w = 128; w > 0; w >>= 1) {
    if ((int)threadIdx.x < w) red[threadIdx.x] += red[threadIdx.x + w];
    __syncthreads();
  }
  if (threadIdx.x == 0) atomicAdd(&mw[blockIdx.y], red[0]);
}

// ---------------------------------------------------------------------------
// 2. ternary-quantize weights, packed COL-major: wp2[mat][o][k4]. grid 768x256.
// ---------------------------------------------------------------------------
__global__ __launch_bounds__(256) void wquant_kernel(
    const float* __restrict__ Wq, const float* __restrict__ Wk,
    const float* __restrict__ Wv, const float* __restrict__ mw,
    int* __restrict__ wp) {
  int idx = blockIdx.x * 256 + threadIdx.x;   // 0 .. 196607
  int mat = idx >> 16;
  int local = idx & 0xFFFF;
  int o  = local >> 7;       // 0..511
  int k4 = local & 127;      // 0..127
  const float* W = mat == 0 ? Wq : (mat == 1 ? Wk : Wv);
  float mean = mw[mat] * (1.0f / 262144.0f);
  float scale = 1.0f / fmaxf(mean, EPSQ);
  float4 w4 = *(const float4*)(W + (size_t)o * DDIM + k4 * 4);
  int t0 = (int)rintf(w4.x * scale); t0 = t0 < -1 ? -1 : (t0 > 1 ? 1 : t0);
  int t1 = (int)rintf(w4.y * scale); t1 = t1 < -1 ? -1 : (t1 > 1 ? 1 : t1);
  int t2 = (int)rintf(w4.z * scale); t2 = t2 < -1 ? -1 : (t2 > 1 ? 1 : t2);
  int t3 = (int)rintf(w4.w * scale); t3 = t3 < -1 ? -1 : (t3 > 1 ? 1 : t3);
  int packed = (t0 & 0xff) | ((t1 & 0xff) << 8) | ((t2 & 0xff) << 16) | ((t3 & 0xff) << 24);
  wp[((size_t)mat * DDIM + o) * KPACK + k4] = packed;
}

// ---------------------------------------------------------------------------
// 3. per-token int8 absmax quantization. One wave per 512-elem row.
// ---------------------------------------------------------------------------
__global__ __launch_bounds__(256) void aquant_kernel(
    const float* __restrict__ x, int* __restrict__ xq, float* __restrict__ sx) {
  int wid = threadIdx.x >> 6, lane = threadIdx.x & 63;
  int row = blockIdx.x * 4 + wid;
  const float* xr = x + (size_t)row * DDIM;
  float4 a = ((const float4*)xr)[lane];        // k = 4*lane .. +3
  float4 b = ((const float4*)xr)[64 + lane];   // k = 256+4*lane .. +3
  float amax = fmaxf(fmaxf(fmaxf(fabsf(a.x), fabsf(a.y)), fmaxf(fabsf(a.z), fabsf(a.w))),
                     fmaxf(fmaxf(fabsf(b.x), fabsf(b.y)), fmaxf(fabsf(b.z), fabsf(b.w))));
  for (int off = 32; off > 0; off >>= 1) amax = fmaxf(amax, __shfl_xor(amax, off, 64));
  float aa = fmaxf(amax, EPSQ);
  float scale = 127.0f / aa;
  int p0 = q8(a.x, scale) | (q8(a.y, scale) << 8) | (q8(a.z, scale) << 16) | (q8(a.w, scale) << 24);
  int p1 = q8(b.x, scale) | (q8(b.y, scale) << 8) | (q8(b.z, scale) << 16) | (q8(b.w, scale) << 24);
  xq[(size_t)row * KPACK + lane]      = p0;    // k4 = lane
  xq[(size_t)row * KPACK + 64 + lane] = p1;    // k4 = 64+lane
  if (lane == 0) sx[row] = aa * (1.0f / 127.0f);
}

// ---------------------------------------------------------------------------
// 4. int8 x ternary GEMM via i8 MFMA. grid (256, 8, 3), block 256 (4 waves).
//    Tile 64 rows x 64 cols, K=512. A=xq rows, B=wp2 cols, both LDS-staged
//    with +4-int pad. i8 16x16x64 frags: A[m=lane&15][k=quad*16+j],
//    B[k=quad*16+j][n=lane&15], C col=lane&15,row=quad*4+reg (dtype-indep).
//    mats 0,1 (Q,K): natural [row][dim]. mat 2 (V): tiled-transposed
//    vT[b][kt][dim][key&31] so each flash V-tile is contiguous 32 KB.
// ---------------------------------------------------------------------------
__global__ __launch_bounds__(256, 2) void qkv_gemm_kernel(
    const int* __restrict__ xq, const int* __restrict__ wp,
    const float* __restrict__ sx, const float* __restrict__ mw,
    _Float16* __restrict__ qkv) {
  __shared__ __align__(16) int xs[64][132];   // A-tile, padded
  __shared__ __align__(16) int bs[64][132];   // B-tile (col-major), padded
  __shared__ float sxs[64];

  const int tid  = threadIdx.x;
  const int w    = tid >> 6;
  const int lane = tid & 63;
  const int quad = lane >> 4;
  const int col  = lane & 15;

  const int r0g = blockIdx.x * 64;      // row block
  const int n0  = blockIdx.y * 64;      // col block
  const int mat = blockIdx.z;

  // stage A: 64 rows x 128 ints (2048 int4 units)
  {
    const i32x4* src = (const i32x4*)(xq + (size_t)r0g * KPACK);
    #pragma unroll
    for (int i = 0; i < 8; i++) {
      int e = i * 256 + tid;
      int row = e >> 5, u = e & 31;
      *(i32x4*)&xs[row][u * 4] = src[e];
    }
  }
  // stage B: 64 cols x 128 ints
  {
    const i32x4* src = (const i32x4*)(wp + ((size_t)mat * DDIM + n0) * KPACK);
    #pragma unroll
    for (int i = 0; i < 8; i++) {
      int e = i * 256 + tid;
      int c = e >> 5, u = e & 31;
      *(i32x4*)&bs[c][u * 4] = src[e];
    }
  }
  if (tid < 64) sxs[tid] = sx[r0g + tid];
  __syncthreads();

  i32x4 acc[4];
  #pragma unroll
  for (int rt = 0; rt < 4; rt++) acc[rt] = (i32x4)(0);

  #pragma unroll
  for (int s = 0; s < 8; s++) {
    i32x4 bf = *(const i32x4*)&bs[w * 16 + col][s * 16 + quad * 4];
    #pragma unroll
    for (int rt = 0; rt < 4; rt++) {
      i32x4 af = *(const i32x4*)&xs[rt * 16 + col][s * 16 + quad * 4];
      acc[rt] = __builtin_amdgcn_mfma_i32_16x16x64_i8(af, bf, acc[rt], 0, 0, 0);
    }
  }

  const float mval = fmaxf(mw[mat] * (1.0f / 262144.0f), EPSQ);
  const int nw = n0 + w * 16 + col;     // this lane's output column

  if (mat < 2) {
    _Float16* outb = qkv + (size_t)mat * NROW * DDIM;
    #pragma unroll
    for (int rt = 0; rt < 4; rt++) {
      #pragma unroll
      for (int reg = 0; reg < 4; reg++) {
        int rowl = rt * 16 + quad * 4 + reg;
        outb[(size_t)(r0g + rowl) * DDIM + nw] =
            (_Float16)((float)acc[rt][reg] * sxs[rowl] * mval);
      }
    }
  } else {
    _Float16* vT = qkv + (size_t)2 * NROW * DDIM;
    #pragma unroll
    for (int rt = 0; rt < 4; rt++) {
      half4 hv;
      #pragma unroll
      for (int reg = 0; reg < 4; reg++) {
        int rowl = rt * 16 + quad * 4 + reg;
        hv[reg] = (_Float16)((float)acc[rt][reg] * sxs[rowl] * mval);
      }
      int r = r0g + rt * 16 + quad * 4;          // first of 4 consecutive keys
      int b = r >> 11, kt = (r & 2047) >> 5, kin = r & 31;
      *(half4*)(vT + ((((size_t)b * 64 + kt) * 512 + nw) * 32 + kin)) = hv;
    }
  }
}

// ---------------------------------------------------------------------------
// 5. f16 MFMA flash attention, causal, scale 8^-0.5.  (unchanged from r8)
// ---------------------------------------------------------------------------
__global__ __launch_bounds__(512, 2) void flash_kernel(
    const _Float16* __restrict__ q, const _Float16* __restrict__ k,
    const _Float16* __restrict__ vT, float* __restrict__ out) {
  __shared__ __align__(16) _Float16 Ksh[2][32][520];  // 66,560 B (DMA rows)
  __shared__ __align__(16) _Float16 VtL[2][512][32];  // 65,536 B (DMA, swizzled)
  __shared__ __align__(16) float    PsS[64 * 33];     // raw scores
  __shared__ __align__(16) _Float16 Pf[64 * 40];      // probabilities
  __shared__ float alpha_l[64];
  __shared__ float invl_l[64];

  const int tid  = threadIdx.x;
  const int w    = tid >> 6;        // 0..7
  const int lane = tid & 63;
  const int quad = lane >> 4;
  const int col  = lane & 15;
  const int rt   = w & 3;           // score row-tile
  const int kh   = w >> 2;          // score key-half
  const int smrow = tid >> 3;       // softmax row 0..63
  const int sme   = tid & 7;        // softmax key group 0..7
  const int d0  = w * 64;           // PV dim slice

  const int vrl = lane >> 2;        // V-DMA row-in-group 0..15
  const int vu  = lane & 3;         // V-DMA 16B unit 0..3

  const int qi = blockIdx.x, batch = blockIdx.y;

  for (int ph = 0; ph < 2; ph++) {
    const int qt = ph ? (31 - qi) : qi;
    const int bb = ph ? (batch ^ 1) : batch;
    const int qrow0 = qt * 64;
    const size_t bbase = (size_t)bb * SEQ * DDIM;
    const _Float16* kb_p = k + bbase;
    const _Float16* vt_p = vT + (size_t)bb * 64 * 512 * 32;  // [kt][dim][key]

    half8 qfrag[16];
    {
      const _Float16* qrow_p = q + bbase + (size_t)(qrow0 + rt * 16 + col) * DDIM;
      #pragma unroll
      for (int s = 0; s < 16; s++)
        qfrag[s] = *(const half8*)(qrow_p + s * 32 + quad * 8);
    }

    float m_run = -INFINITY, l_run = 0.f;
    f32x4 o[4][4];
    #pragma unroll
    for (int a = 0; a < 4; a++)
      #pragma unroll
      for (int b = 0; b < 4; b++) o[a][b] = (f32x4)(0.f);

    const int ntiles = 2 * (qt + 1);

    #pragma unroll
    for (int i = 0; i < 4; i++)
      gld_lds16(kb_p + (size_t)(w * 4 + i) * DDIM + lane * 8, &Ksh[0][w * 4 + i][0]);
    #pragma unroll
    for (int i = 0; i < 4; i++) {
      int r = w * 64 + i * 16 + vrl;
      int su = vu ^ ((r >> 1) & 3);
      gld_lds16(vt_p + (size_t)r * 32 + su * 8, &VtL[0][w * 64 + i * 16][0]);
    }
    __syncthreads();

    for (int kt = 0; kt < ntiles; kt++) {
      const int cur = kt & 1, nxt = cur ^ 1;
      const int kb0 = kt * 32;

      if (kt + 1 < ntiles) {
        const int kb1 = kb0 + 32;
        #pragma unroll
        for (int i = 0; i < 4; i++)
          gld_lds16(kb_p + (size_t)(kb1 + w * 4 + i) * DDIM + lane * 8,
                    &Ksh[nxt][w * 4 + i][0]);
        const _Float16* vtile = vt_p + (size_t)(kt + 1) * 512 * 32;
        #pragma unroll
        for (int i = 0; i < 4; i++) {
          int r = w * 64 + i * 16 + vrl;
          int su = vu ^ ((r >> 1) & 3);
          gld_lds16(vtile + (size_t)r * 32 + su * 8, &VtL[nxt][w * 64 + i * 16][0]);
        }
      }

      {
        f32x4 c = (f32x4)(0.f);
        #pragma unroll
        for (int s = 0; s < 16; s++) {
          half8 b = *(const half8*)&Ksh[cur][kh * 16 + col][s * 32 + quad * 8];
          c = __builtin_amdgcn_mfma_f32_16x16x32_f16(qfrag[s], b, c, 0, 0, 0);
        }
        #pragma unroll
        for (int reg = 0; reg < 4; reg++)
          PsS[(rt * 16 + quad * 4 + reg) * 33 + kh * 16 + col] = c[reg];
      }
      __syncthreads();   // B: scores ready (drains DMA prefetch)

      {
        const int qrow = qrow0 + smrow;
        float sv[4];
        #pragma unroll
        for (int i = 0; i < 4; i++) {
          float s = PsS[smrow * 33 + sme * 4 + i] * FSCALE;
          if (kb0 + sme * 4 + i > qrow) s = -INFINITY;
          sv[i] = s;
        }
        float mx = fmaxf(fmaxf(sv[0], sv[1]), fmaxf(sv[2], sv[3]));
        #pragma unroll
        for (int m = 1; m <= 4; m <<= 1) mx = fmaxf(mx, __shfl_xor(mx, m, 64));
        float mn = fmaxf(m_run, mx);
        float al = __expf(m_run - mn);
        half4 p4;
        float rs = 0.f;
        #pragma unroll
        for (int i = 0; i < 4; i++) {
          float p = __expf(sv[i] - mn);
          rs += p;
          p4[i] = (_Float16)p;
        }
        #pragma unroll
        for (int m = 1; m <= 4; m <<= 1) rs += __shfl_xor(rs, m, 64);
        l_run = l_run * al + rs;
        m_run = mn;
        *(half4*)&Pf[smrow * 40 + sme * 4] = p4;
        if (sme == 0) alpha_l[smrow] = al;
      }
      __syncthreads();   // C: Pf + alpha ready

      {
        half8 ap[4];
        f32x4 af[4];
        #pragma unroll
        for (int r2 = 0; r2 < 4; r2++) {
          ap[r2] = *(const half8*)&Pf[(r2 * 16 + col) * 40 + quad * 8];
          af[r2] = *(const f32x4*)&alpha_l[r2 * 16 + quad * 4];
        }
        #pragma unroll
        for (int r2 = 0; r2 < 4; r2++)
          #pragma unroll
          for (int ct = 0; ct < 4; ct++)
            o[r2][ct] *= af[r2];
        #pragma unroll
        for (int ct = 0; ct < 4; ct++) {
          int R = d0 + ct * 16 + col;
          int ur = quad ^ ((R >> 1) & 3);
          half8 bv = *(const half8*)&VtL[cur][R][ur * 8];
          #pragma unroll
          for (int r2 = 0; r2 < 4; r2++)
            o[r2][ct] = __builtin_amdgcn_mfma_f32_16x16x32_f16(ap[r2], bv, o[r2][ct], 0, 0, 0);
        }
      }
      __syncthreads();   // D: PV done; cur bufs may be re-DMA'd next iter
    }

    if (sme == 0) invl_l[smrow] = 1.0f / l_run;
    __syncthreads();
    #pragma unroll
    for (int r2 = 0; r2 < 4; r2++) {
      f32x4 iv = *(const f32x4*)&invl_l[r2 * 16 + quad * 4];
      #pragma unroll
      for (int ct = 0; ct < 4; ct++) {
        #pragma unroll
        for (int e = 0; e < 4; e++) {
          out[((size_t)bb * SEQ + qrow0 + r2 * 16 + quad * 4 + e) * DDIM
              + d0 + ct * 16 + col] = o[r2][ct][e] * iv[e];
        }
      }
    }
    __syncthreads();   // protect LDS before next phase's prologue
  }
}

// ---------------------------------------------------------------------------
extern "C" void kernel_launch(void* const* d_in, const int* in_sizes, int n_in,
                              void* d_out, int out_size, void* d_ws, size_t ws_size,
                              hipStream_t stream) {
  const float* x  = (const float*)d_in[0];
  const float* Wq = (const float*)d_in[1];
  const float* Wk = (const float*)d_in[2];
  const float* Wv = (const float*)d_in[3];
  float* out = (float*)d_out;
  char* ws = (char*)d_ws;

  float* mw  = (float*)(ws + OFF_M);
  int*   wp  = (int*)(ws + OFF_WP);
  int*   xq  = (int*)(ws + OFF_XQ);
  float* sx  = (float*)(ws + OFF_SX);
  _Float16* qkv = (_Float16*)(ws + OFF_QKV);
  _Float16* qf  = qkv;
  _Float16* kf  = qkv + (size_t)NROW * DDIM;
  _Float16* vTf = qkv + 2 * (size_t)NROW * DDIM;

  hipMemsetAsync(mw, 0, 16, stream);
  wsum_kernel<<<dim3(32, 3), 256, 0, stream>>>(Wq, Wk, Wv, mw);
  wquant_kernel<<<768, 256, 0, stream>>>(Wq, Wk, Wv, mw, wp);
  aquant_kernel<<<4096, 256, 0, stream>>>(x, xq, sx);
  qkv_gemm_kernel<<<dim3(256, 8, 3), 256, 0, stream>>>(xq, wp, sx, mw, qkv);
  flash_kernel<<<dim3(32, 8), 512, 0, stream>>>(qf, kf, vTf, out);
}

// Round 10
// 288.886 us; speedup vs baseline: 2.0056x; 1.0112x over previous
//
#include <hip/hip_runtime.h>
#include <cstdint>
#include <cstddef>

// Problem shape (fixed by setup_inputs): B=8, S=2048, D=512. All tensors f32.
#define BATCH 8
#define SEQ   2048
#define DDIM  512
#define NROW  (BATCH*SEQ)          // 16384 token rows
#define KPACK (DDIM/4)             // 128 packed int32 per row
#define EPSQ  1e-5f
#define FSCALE 0.35355339059327373f  // 8 ** -0.5

typedef _Float16 half8 __attribute__((ext_vector_type(8)));
typedef _Float16 half4 __attribute__((ext_vector_type(4)));
typedef float    f32x4 __attribute__((ext_vector_type(4)));
typedef int      i32x4 __attribute__((ext_vector_type(4)));

// Workspace layout (bytes)
static constexpr size_t OFF_M   = 0;                                   // 3 floats abs-sum
static constexpr size_t OFF_WP  = 256;                                 // 3*512*128 int32 (col-major)
static constexpr size_t OFF_XQ  = OFF_WP + (size_t)3*KPACK*DDIM*4;     // 16384*128 int32
static constexpr size_t OFF_SX  = OFF_XQ + (size_t)NROW*KPACK*4;       // 16384 f32
static constexpr size_t OFF_QKV = OFF_SX + (size_t)NROW*4;             // 3*16384*512 f16
static constexpr size_t OFF_PO  = OFF_QKV + (size_t)3*NROW*DDIM*2;     // 512*64*512 f32 partial O
static constexpr size_t OFF_PM  = OFF_PO + (size_t)512*64*512*4;       // 512*64 f32 m
static constexpr size_t OFF_PL  = OFF_PM + (size_t)512*64*4;           // 512*64 f32 l

__device__ __forceinline__ int q8(float v, float s) {
  int i = (int)rintf(v * s);
  i = i < -128 ? -128 : (i > 127 ? 127 : i);
  return i & 0xff;
}

// async global->LDS DMA, 16B per lane; lds dest = wave-uniform base + lane*16
__device__ __forceinline__ void gld_lds16(const _Float16* g, _Float16* l) {
  __builtin_amdgcn_global_load_lds(
      (const __attribute__((address_space(1))) void*)g,
      (__attribute__((address_space(3))) void*)l, 16, 0, 0);
}

// ---------------------------------------------------------------------------
// 1. abs-sum of each weight matrix. grid (32,3), block 256; mw pre-zeroed.
// ---------------------------------------------------------------------------
__global__ __launch_bounds__(256) void wsum_kernel(
    const float* __restrict__ Wq, const float* __restrict__ Wk,
    const float* __restrict__ Wv, float* __restrict__ mw) {
  const float* W = blockIdx.y == 0 ? Wq : (blockIdx.y == 1 ? Wk : Wv);
  __shared__ float red[256];
  const float4* p = (const float4*)(W + blockIdx.x * 8192);
  float s = 0.f;
  #pragma unroll
  for (int i = 0; i < 8; i++) {
    float4 a = p[i * 256 + threadIdx.x];
    s += fabsf(a.x) + fabsf(a.y) + fabsf(a.z) + fabsf(a.w);
  }
  red[threadIdx.x] = s;
  __syncthreads();
  for (int w = 128; w > 0; w >>= 1) {
    if ((int)threadIdx.x < w) red[threadIdx.x] += red[threadIdx.x + w];
    __syncthreads();
  }
  if (threadIdx.x == 0) atomicAdd(&mw[blockIdx.y], red[0]);
}

// ---------------------------------------------------------------------------
// 2. ternary-quantize weights, packed COL-major: wp2[mat][o][k4]. grid 768x256.
// ---------------------------------------------------------------------------
__global__ __launch_bounds__(256) void wquant_kernel(
    const float* __restrict__ Wq, const float* __restrict__ Wk,
    const float* __restrict__ Wv, const float* __restrict__ mw,
    int* __restrict__ wp) {
  int idx = blockIdx.x * 256 + threadIdx.x;   // 0 .. 196607
  int mat = idx >> 16;
  int local = idx & 0xFFFF;
  int o  = local >> 7;       // 0..511
  int k4 = local & 127;      // 0..127
  const float* W = mat == 0 ? Wq : (mat == 1 ? Wk : Wv);
  float mean = mw[mat] * (1.0f / 262144.0f);
  float scale = 1.0f / fmaxf(mean, EPSQ);
  float4 w4 = *(const float4*)(W + (size_t)o * DDIM + k4 * 4);
  int t0 = (int)rintf(w4.x * scale); t0 = t0 < -1 ? -1 : (t0 > 1 ? 1 : t0);
  int t1 = (int)rintf(w4.y * scale); t1 = t1 < -1 ? -1 : (t1 > 1 ? 1 : t1);
  int t2 = (int)rintf(w4.z * scale); t2 = t2 < -1 ? -1 : (t2 > 1 ? 1 : t2);
  int t3 = (int)rintf(w4.w * scale); t3 = t3 < -1 ? -1 : (t3 > 1 ? 1 : t3);
  int packed = (t0 & 0xff) | ((t1 & 0xff) << 8) | ((t2 & 0xff) << 16) | ((t3 & 0xff) << 24);
  wp[((size_t)mat * DDIM + o) * KPACK + k4] = packed;
}

// ---------------------------------------------------------------------------
// 3. per-token int8 absmax quantization. One wave per 512-elem row.
// ---------------------------------------------------------------------------
__global__ __launch_bounds__(256) void aquant_kernel(
    const float* __restrict__ x, int* __restrict__ xq, float* __restrict__ sx) {
  int wid = threadIdx.x >> 6, lane = threadIdx.x & 63;
  int row = blockIdx.x * 4 + wid;
  const float* xr = x + (size_t)row * DDIM;
  float4 a = ((const float4*)xr)[lane];        // k = 4*lane .. +3
  float4 b = ((const float4*)xr)[64 + lane];   // k = 256+4*lane .. +3
  float amax = fmaxf(fmaxf(fmaxf(fabsf(a.x), fabsf(a.y)), fmaxf(fabsf(a.z), fabsf(a.w))),
                     fmaxf(fmaxf(fabsf(b.x), fabsf(b.y)), fmaxf(fabsf(b.z), fabsf(b.w))));
  for (int off = 32; off > 0; off >>= 1) amax = fmaxf(amax, __shfl_xor(amax, off, 64));
  float aa = fmaxf(amax, EPSQ);
  float scale = 127.0f / aa;
  int p0 = q8(a.x, scale) | (q8(a.y, scale) << 8) | (q8(a.z, scale) << 16) | (q8(a.w, scale) << 24);
  int p1 = q8(b.x, scale) | (q8(b.y, scale) << 8) | (q8(b.z, scale) << 16) | (q8(b.w, scale) << 24);
  xq[(size_t)row * KPACK + lane]      = p0;    // k4 = lane
  xq[(size_t)row * KPACK + 64 + lane] = p1;    // k4 = 64+lane
  if (lane == 0) sx[row] = aa * (1.0f / 127.0f);
}

// ---------------------------------------------------------------------------
// 4. int8 x ternary GEMM via i8 MFMA. grid (256, 8, 3), block 256 (4 waves).
//    (unchanged from r9 — bench-verified)
// ---------------------------------------------------------------------------
__global__ __launch_bounds__(256, 2) void qkv_gemm_kernel(
    const int* __restrict__ xq, const int* __restrict__ wp,
    const float* __restrict__ sx, const float* __restrict__ mw,
    _Float16* __restrict__ qkv) {
  __shared__ __align__(16) int xs[64][132];   // A-tile, padded
  __shared__ __align__(16) int bs[64][132];   // B-tile (col-major), padded
  __shared__ float sxs[64];

  const int tid  = threadIdx.x;
  const int w    = tid >> 6;
  const int lane = tid & 63;
  const int quad = lane >> 4;
  const int col  = lane & 15;

  const int r0g = blockIdx.x * 64;      // row block
  const int n0  = blockIdx.y * 64;      // col block
  const int mat = blockIdx.z;

  {
    const i32x4* src = (const i32x4*)(xq + (size_t)r0g * KPACK);
    #pragma unroll
    for (int i = 0; i < 8; i++) {
      int e = i * 256 + tid;
      int row = e >> 5, u = e & 31;
      *(i32x4*)&xs[row][u * 4] = src[e];
    }
  }
  {
    const i32x4* src = (const i32x4*)(wp + ((size_t)mat * DDIM + n0) * KPACK);
    #pragma unroll
    for (int i = 0; i < 8; i++) {
      int e = i * 256 + tid;
      int c = e >> 5, u = e & 31;
      *(i32x4*)&bs[c][u * 4] = src[e];
    }
  }
  if (tid < 64) sxs[tid] = sx[r0g + tid];
  __syncthreads();

  i32x4 acc[4];
  #pragma unroll
  for (int rt = 0; rt < 4; rt++) acc[rt] = (i32x4)(0);

  #pragma unroll
  for (int s = 0; s < 8; s++) {
    i32x4 bf = *(const i32x4*)&bs[w * 16 + col][s * 16 + quad * 4];
    #pragma unroll
    for (int rt = 0; rt < 4; rt++) {
      i32x4 af = *(const i32x4*)&xs[rt * 16 + col][s * 16 + quad * 4];
      acc[rt] = __builtin_amdgcn_mfma_i32_16x16x64_i8(af, bf, acc[rt], 0, 0, 0);
    }
  }

  const float mval = fmaxf(mw[mat] * (1.0f / 262144.0f), EPSQ);
  const int nw = n0 + w * 16 + col;     // this lane's output column

  if (mat < 2) {
    _Float16* outb = qkv + (size_t)mat * NROW * DDIM;
    #pragma unroll
    for (int rt = 0; rt < 4; rt++) {
      #pragma unroll
      for (int reg = 0; reg < 4; reg++) {
        int rowl = rt * 16 + quad * 4 + reg;
        outb[(size_t)(r0g + rowl) * DDIM + nw] =
            (_Float16)((float)acc[rt][reg] * sxs[rowl] * mval);
      }
    }
  } else {
    _Float16* vT = qkv + (size_t)2 * NROW * DDIM;
    #pragma unroll
    for (int rt = 0; rt < 4; rt++) {
      half4 hv;
      #pragma unroll
      for (int reg = 0; reg < 4; reg++) {
        int rowl = rt * 16 + quad * 4 + reg;
        hv[reg] = (_Float16)((float)acc[rt][reg] * sxs[rowl] * mval);
      }
      int r = r0g + rt * 16 + quad * 4;          // first of 4 consecutive keys
      int b = r >> 11, kt = (r & 2047) >> 5, kin = r & 31;
      *(half4*)(vT + ((((size_t)b * 64 + kt) * 512 + nw) * 32 + kin)) = hv;
    }
  }
}

// ---------------------------------------------------------------------------
// 5. f16 MFMA flash attention, split-K slots. Grid (64,8), block 512.
//    Slot x: qt = 31-(x>>1) (heavy-first dispatch), h = x&1. Slot processes
//    key-tiles h, h+2, ... (qt+1 tiles) of unit (qt, batch); writes
//    UNNORMALIZED partial O (f32) + per-row m,l to workspace. Inner per-tile
//    code identical to r8/r9 (bench-verified); -1e30 clamp in exp args
//    guards rows whose slot-tiles are fully causal-masked.
// ---------------------------------------------------------------------------
__global__ __launch_bounds__(512, 2) void flash_kernel(
    const _Float16* __restrict__ q, const _Float16* __restrict__ k,
    const _Float16* __restrict__ vT, float* __restrict__ po,
    float* __restrict__ pm, float* __restrict__ pl) {
  __shared__ __align__(16) _Float16 Ksh[2][32][520];  // DMA rows
  __shared__ __align__(16) _Float16 VtL[2][512][32];  // DMA, swizzled
  __shared__ __align__(16) float    PsS[64 * 33];     // raw scores
  __shared__ __align__(16) _Float16 Pf[64 * 40];      // probabilities
  __shared__ float alpha_l[64];

  const int tid  = threadIdx.x;
  const int w    = tid >> 6;        // 0..7
  const int lane = tid & 63;
  const int quad = lane >> 4;
  const int col  = lane & 15;
  const int rt   = w & 3;           // score row-tile
  const int kh   = w >> 2;          // score key-half
  const int smrow = tid >> 3;       // softmax row 0..63
  const int sme   = tid & 7;        // softmax key group 0..7
  const int d0  = w * 64;           // PV dim slice

  const int vrl = lane >> 2;        // V-DMA row-in-group 0..15
  const int vu  = lane & 3;         // V-DMA 16B unit 0..3

  const int x  = blockIdx.x;        // 0..63
  const int bb = blockIdx.y;        // 0..7
  const int qt = 31 - (x >> 1);     // heavy slots dispatched first
  const int h  = x & 1;             // key-tile parity
  const int slot = ((qt * 8 + bb) * 2 + h);
  const int nT = qt + 1;            // tiles in this slot

  const int qrow0 = qt * 64;
  const size_t bbase = (size_t)bb * SEQ * DDIM;
  const _Float16* kb_p = k + bbase;
  const _Float16* vt_p = vT + (size_t)bb * 64 * 512 * 32;  // [kt][dim][key]

  half8 qfrag[16];
  {
    const _Float16* qrow_p = q + bbase + (size_t)(qrow0 + rt * 16 + col) * DDIM;
    #pragma unroll
    for (int s = 0; s < 16; s++)
      qfrag[s] = *(const half8*)(qrow_p + s * 32 + quad * 8);
  }

  float m_run = -INFINITY, l_run = 0.f;
  f32x4 o[4][4];
  #pragma unroll
  for (int a = 0; a < 4; a++)
    #pragma unroll
    for (int b2 = 0; b2 < 4; b2++) o[a][b2] = (f32x4)(0.f);

  // prologue: DMA K tile h + V tile h into buf 0
  #pragma unroll
  for (int i = 0; i < 4; i++)
    gld_lds16(kb_p + (size_t)(h * 32 + w * 4 + i) * DDIM + lane * 8,
              &Ksh[0][w * 4 + i][0]);
  {
    const _Float16* vtile = vt_p + (size_t)h * 512 * 32;
    #pragma unroll
    for (int i = 0; i < 4; i++) {
      int r = w * 64 + i * 16 + vrl;
      int su = vu ^ ((r >> 1) & 3);
      gld_lds16(vtile + (size_t)r * 32 + su * 8, &VtL[0][w * 64 + i * 16][0]);
    }
  }
  __syncthreads();

  for (int t = 0; t < nT; t++) {
    const int cur = t & 1, nxt = cur ^ 1;
    const int kb0 = (2 * t + h) * 32;

    // prefetch this slot's next tile (stride 2) — drains at barrier B
    if (t + 1 < nT) {
      const int kb1 = kb0 + 64;
      #pragma unroll
      for (int i = 0; i < 4; i++)
        gld_lds16(kb_p + (size_t)(kb1 + w * 4 + i) * DDIM + lane * 8,
                  &Ksh[nxt][w * 4 + i][0]);
      const _Float16* vtile = vt_p + (size_t)(2 * t + h + 2) * 512 * 32;
      #pragma unroll
      for (int i = 0; i < 4; i++) {
        int r = w * 64 + i * 16 + vrl;
        int su = vu ^ ((r >> 1) & 3);
        gld_lds16(vtile + (size_t)r * 32 + su * 8, &VtL[nxt][w * 64 + i * 16][0]);
      }
    }

    // ---- scores ----
    {
      f32x4 c = (f32x4)(0.f);
      #pragma unroll
      for (int s = 0; s < 16; s++) {
        half8 b = *(const half8*)&Ksh[cur][kh * 16 + col][s * 32 + quad * 8];
        c = __builtin_amdgcn_mfma_f32_16x16x32_f16(qfrag[s], b, c, 0, 0, 0);
      }
      #pragma unroll
      for (int reg = 0; reg < 4; reg++)
        PsS[(rt * 16 + quad * 4 + reg) * 33 + kh * 16 + col] = c[reg];
    }
    __syncthreads();   // B: scores ready (drains DMA prefetch)

    // ---- softmax ----
    {
      const int qrow = qrow0 + smrow;
      float sv[4];
      #pragma unroll
      for (int i = 0; i < 4; i++) {
        float s = PsS[smrow * 33 + sme * 4 + i] * FSCALE;
        if (kb0 + sme * 4 + i > qrow) s = -INFINITY;
        sv[i] = s;
      }
      float mx = fmaxf(fmaxf(sv[0], sv[1]), fmaxf(sv[2], sv[3]));
      #pragma unroll
      for (int m = 1; m <= 4; m <<= 1) mx = fmaxf(mx, __shfl_xor(mx, m, 64));
      float mn = fmaxf(m_run, mx);
      float mnc = fmaxf(mn, -1e30f);     // guard fully-masked rows
      float al = __expf(m_run - mnc);
      half4 p4;
      float rs = 0.f;
      #pragma unroll
      for (int i = 0; i < 4; i++) {
        float p = __expf(sv[i] - mnc);
        rs += p;
        p4[i] = (_Float16)p;
      }
      #pragma unroll
      for (int m = 1; m <= 4; m <<= 1) rs += __shfl_xor(rs, m, 64);
      l_run = l_run * al + rs;
      m_run = mn;
      *(half4*)&Pf[smrow * 40 + sme * 4] = p4;
      if (sme == 0) alpha_l[smrow] = al;
    }
    __syncthreads();   // C: Pf + alpha ready

    // ---- PV ----
    {
      half8 ap[4];
      f32x4 af[4];
      #pragma unroll
      for (int r2 = 0; r2 < 4; r2++) {
        ap[r2] = *(const half8*)&Pf[(r2 * 16 + col) * 40 + quad * 8];
        af[r2] = *(const f32x4*)&alpha_l[r2 * 16 + quad * 4];
      }
      #pragma unroll
      for (int r2 = 0; r2 < 4; r2++)
        #pragma unroll
        for (int ct = 0; ct < 4; ct++)
          o[r2][ct] *= af[r2];
      #pragma unroll
      for (int ct = 0; ct < 4; ct++) {
        int R = d0 + ct * 16 + col;
        int ur = quad ^ ((R >> 1) & 3);
        half8 bv = *(const half8*)&VtL[cur][R][ur * 8];
        #pragma unroll
        for (int r2 = 0; r2 < 4; r2++)
          o[r2][ct] = __builtin_amdgcn_mfma_f32_16x16x32_f16(ap[r2], bv, o[r2][ct], 0, 0, 0);
      }
    }
    __syncthreads();   // D: PV done; cur bufs may be re-DMA'd next iter
  }

  // ---- epilogue: write unnormalized partials + m/l ----
  if (sme == 0) {
    pm[slot * 64 + smrow] = m_run;
    pl[slot * 64 + smrow] = l_run;
  }
  {
    float* pob = po + (size_t)slot * 64 * 512;
    #pragma unroll
    for (int r2 = 0; r2 < 4; r2++) {
      #pragma unroll
      for (int ct = 0; ct < 4; ct++) {
        #pragma unroll
        for (int e = 0; e < 4; e++) {
          pob[(size_t)(r2 * 16 + quad * 4 + e) * 512 + d0 + ct * 16 + col] =
              o[r2][ct][e];
        }
      }
    }
  }
}

// ---------------------------------------------------------------------------
// 6. split-K merge: out = (w0*o0 + w1*o1) / (w0*l0 + w1*l1). grid (32,8).
// ---------------------------------------------------------------------------
__global__ __launch_bounds__(256) void merge_kernel(
    const float* __restrict__ po, const float* __restrict__ pm,
    const float* __restrict__ pl, float* __restrict__ out) {
  __shared__ float w0s[64], w1s[64], dns[64];
  const int tid = threadIdx.x;
  const int qt = blockIdx.x, b = blockIdx.y;
  const int slot0 = (qt * 8 + b) * 2;
  const int slot1 = slot0 + 1;

  if (tid < 64) {
    float m0 = pm[slot0 * 64 + tid], m1 = pm[slot1 * 64 + tid];
    float l0 = pl[slot0 * 64 + tid], l1 = pl[slot1 * 64 + tid];
    float ms = fmaxf(m0, m1);                 // finite: slot0 has diagonal keys
    float a0 = __expf(m0 - ms);               // exp(-inf - finite) = 0 ok
    float a1 = __expf(m1 - ms);
    w0s[tid] = a0;
    w1s[tid] = a1;
    dns[tid] = 1.0f / (a0 * l0 + a1 * l1);
  }
  __syncthreads();

  const f32x4* p0 = (const f32x4*)(po + (size_t)slot0 * 64 * 512);
  const f32x4* p1 = (const f32x4*)(po + (size_t)slot1 * 64 * 512);
  f32x4* op = (f32x4*)(out + ((size_t)b * SEQ + qt * 64) * 512);
  #pragma unroll 4
  for (int j = 0; j < 32; j++) {
    int e = j * 256 + tid;          // f32x4 units, row-major 64x128
    int row = e >> 7;
    f32x4 r = (p0[e] * w0s[row] + p1[e] * w1s[row]) * dns[row];
    op[e] = r;
  }
}

// ---------------------------------------------------------------------------
extern "C" void kernel_launch(void* const* d_in, const int* in_sizes, int n_in,
                              void* d_out, int out_size, void* d_ws, size_t ws_size,
                              hipStream_t stream) {
  const float* x  = (const float*)d_in[0];
  const float* Wq = (const float*)d_in[1];
  const float* Wk = (const float*)d_in[2];
  const float* Wv = (const float*)d_in[3];
  float* out = (float*)d_out;
  char* ws = (char*)d_ws;

  float* mw  = (float*)(ws + OFF_M);
  int*   wp  = (int*)(ws + OFF_WP);
  int*   xq  = (int*)(ws + OFF_XQ);
  float* sx  = (float*)(ws + OFF_SX);
  _Float16* qkv = (_Float16*)(ws + OFF_QKV);
  _Float16* qf  = qkv;
  _Float16* kf  = qkv + (size_t)NROW * DDIM;
  _Float16* vTf = qkv + 2 * (size_t)NROW * DDIM;
  float* po = (float*)(ws + OFF_PO);
  float* pm = (float*)(ws + OFF_PM);
  float* pl = (float*)(ws + OFF_PL);

  hipMemsetAsync(mw, 0, 16, stream);
  wsum_kernel<<<dim3(32, 3), 256, 0, stream>>>(Wq, Wk, Wv, mw);
  wquant_kernel<<<768, 256, 0, stream>>>(Wq, Wk, Wv, mw, wp);
  aquant_kernel<<<4096, 256, 0, stream>>>(x, xq, sx);
  qkv_gemm_kernel<<<dim3(256, 8, 3), 256, 0, stream>>>(xq, wp, sx, mw, qkv);
  flash_kernel<<<dim3(64, 8), 512, 0, stream>>>(qf, kf, vTf, po, pm, pl);
  merge_kernel<<<dim3(32, 8), 256, 0, stream>>>(po, pm, pl, out);
}

// Round 11
// 236.998 us; speedup vs baseline: 2.4447x; 1.2189x over previous
//
#include <hip/hip_runtime.h>
#include <cstdint>
#include <cstddef>

// Problem shape (fixed by setup_inputs): B=8, S=2048, D=512. All tensors f32.
#define BATCH 8
#define SEQ   2048
#define DDIM  512
#define NROW  (BATCH*SEQ)          // 16384 token rows
#define KPACK (DDIM/4)             // 128 packed int32 per row
#define EPSQ  1e-5f
#define FSCALE 0.35355339059327373f  // 8 ** -0.5

typedef _Float16 half8 __attribute__((ext_vector_type(8)));
typedef _Float16 half4 __attribute__((ext_vector_type(4)));
typedef float    f32x4 __attribute__((ext_vector_type(4)));
typedef int      i32x4 __attribute__((ext_vector_type(4)));

// Workspace layout (bytes)
static constexpr size_t OFF_M   = 0;                                   // 3 floats abs-sum
static constexpr size_t OFF_WP  = 256;                                 // 3*512*128 int32 (col-major)
static constexpr size_t OFF_XQ  = OFF_WP + (size_t)3*KPACK*DDIM*4;     // 16384*128 int32
static constexpr size_t OFF_SX  = OFF_XQ + (size_t)NROW*KPACK*4;       // 16384 f32
static constexpr size_t OFF_QKV = OFF_SX + (size_t)NROW*4;             // 3*16384*512 f16
static constexpr size_t OFF_PO  = OFF_QKV + (size_t)3*NROW*DDIM*2;     // 512*64*512 f32 partial O
static constexpr size_t OFF_PM  = OFF_PO + (size_t)512*64*512*4;       // 512*64 f32 m
static constexpr size_t OFF_PL  = OFF_PM + (size_t)512*64*4;           // 512*64 f32 l

__device__ __forceinline__ int q8(float v, float s) {
  int i = (int)rintf(v * s);
  i = i < -128 ? -128 : (i > 127 ? 127 : i);
  return i & 0xff;
}

// async global->LDS DMA, 16B per lane; lds dest = wave-uniform base + lane*16
__device__ __forceinline__ void gld_lds16(const _Float16* g, _Float16* l) {
  __builtin_amdgcn_global_load_lds(
      (const __attribute__((address_space(1))) void*)g,
      (__attribute__((address_space(3))) void*)l, 16, 0, 0);
}

// ---------------------------------------------------------------------------
// 1. abs-sum of each weight matrix. grid (32,3), block 256; mw pre-zeroed.
// ---------------------------------------------------------------------------
__global__ __launch_bounds__(256) void wsum_kernel(
    const float* __restrict__ Wq, const float* __restrict__ Wk,
    const float* __restrict__ Wv, float* __restrict__ mw) {
  const float* W = blockIdx.y == 0 ? Wq : (blockIdx.y == 1 ? Wk : Wv);
  __shared__ float red[256];
  const float4* p = (const float4*)(W + blockIdx.x * 8192);
  float s = 0.f;
  #pragma unroll
  for (int i = 0; i < 8; i++) {
    float4 a = p[i * 256 + threadIdx.x];
    s += fabsf(a.x) + fabsf(a.y) + fabsf(a.z) + fabsf(a.w);
  }
  red[threadIdx.x] = s;
  __syncthreads();
  for (int w = 128; w > 0; w >>= 1) {
    if ((int)threadIdx.x < w) red[threadIdx.x] += red[threadIdx.x + w];
    __syncthreads();
  }
  if (threadIdx.x == 0) atomicAdd(&mw[blockIdx.y], red[0]);
}

// ---------------------------------------------------------------------------
// 2. ternary-quantize weights, packed COL-major: wp2[mat][o][k4]. grid 768x256.
// ---------------------------------------------------------------------------
__global__ __launch_bounds__(256) void wquant_kernel(
    const float* __restrict__ Wq, const float* __restrict__ Wk,
    const float* __restrict__ Wv, const float* __restrict__ mw,
    int* __restrict__ wp) {
  int idx = blockIdx.x * 256 + threadIdx.x;   // 0 .. 196607
  int mat = idx >> 16;
  int local = idx & 0xFFFF;
  int o  = local >> 7;       // 0..511
  int k4 = local & 127;      // 0..127
  const float* W = mat == 0 ? Wq : (mat == 1 ? Wk : Wv);
  float mean = mw[mat] * (1.0f / 262144.0f);
  float scale = 1.0f / fmaxf(mean, EPSQ);
  float4 w4 = *(const float4*)(W + (size_t)o * DDIM + k4 * 4);
  int t0 = (int)rintf(w4.x * scale); t0 = t0 < -1 ? -1 : (t0 > 1 ? 1 : t0);
  int t1 = (int)rintf(w4.y * scale); t1 = t1 < -1 ? -1 : (t1 > 1 ? 1 : t1);
  int t2 = (int)rintf(w4.z * scale); t2 = t2 < -1 ? -1 : (t2 > 1 ? 1 : t2);
  int t3 = (int)rintf(w4.w * scale); t3 = t3 < -1 ? -1 : (t3 > 1 ? 1 : t3);
  int packed = (t0 & 0xff) | ((t1 & 0xff) << 8) | ((t2 & 0xff) << 16) | ((t3 & 0xff) << 24);
  wp[((size_t)mat * DDIM + o) * KPACK + k4] = packed;
}

// ---------------------------------------------------------------------------
// 3. per-token int8 absmax quantization. One wave per 512-elem row.
// ---------------------------------------------------------------------------
__global__ __launch_bounds__(256) void aquant_kernel(
    const float* __restrict__ x, int* __restrict__ xq, float* __restrict__ sx) {
  int wid = threadIdx.x >> 6, lane = threadIdx.x & 63;
  int row = blockIdx.x * 4 + wid;
  const float* xr = x + (size_t)row * DDIM;
  float4 a = ((const float4*)xr)[lane];        // k = 4*lane .. +3
  float4 b = ((const float4*)xr)[64 + lane];   // k = 256+4*lane .. +3
  float amax = fmaxf(fmaxf(fmaxf(fabsf(a.x), fabsf(a.y)), fmaxf(fabsf(a.z), fabsf(a.w))),
                     fmaxf(fmaxf(fabsf(b.x), fabsf(b.y)), fmaxf(fabsf(b.z), fabsf(b.w))));
  for (int off = 32; off > 0; off >>= 1) amax = fmaxf(amax, __shfl_xor(amax, off, 64));
  float aa = fmaxf(amax, EPSQ);
  float scale = 127.0f / aa;
  int p0 = q8(a.x, scale) | (q8(a.y, scale) << 8) | (q8(a.z, scale) << 16) | (q8(a.w, scale) << 24);
  int p1 = q8(b.x, scale) | (q8(b.y, scale) << 8) | (q8(b.z, scale) << 16) | (q8(b.w, scale) << 24);
  xq[(size_t)row * KPACK + lane]      = p0;    // k4 = lane
  xq[(size_t)row * KPACK + 64 + lane] = p1;    // k4 = 64+lane
  if (lane == 0) sx[row] = aa * (1.0f / 127.0f);
}

// ---------------------------------------------------------------------------
// 4. int8 x ternary GEMM via i8 MFMA. grid (256, 8, 3), block 256 (4 waves).
//    (unchanged from r9/r10 — bench-verified)
// ---------------------------------------------------------------------------
__global__ __launch_bounds__(256, 2) void qkv_gemm_kernel(
    const int* __restrict__ xq, const int* __restrict__ wp,
    const float* __restrict__ sx, const float* __restrict__ mw,
    _Float16* __restrict__ qkv) {
  __shared__ __align__(16) int xs[64][132];   // A-tile, padded
  __shared__ __align__(16) int bs[64][132];   // B-tile (col-major), padded
  __shared__ float sxs[64];

  const int tid  = threadIdx.x;
  const int w    = tid >> 6;
  const int lane = tid & 63;
  const int quad = lane >> 4;
  const int col  = lane & 15;

  const int r0g = blockIdx.x * 64;      // row block
  const int n0  = blockIdx.y * 64;      // col block
  const int mat = blockIdx.z;

  {
    const i32x4* src = (const i32x4*)(xq + (size_t)r0g * KPACK);
    #pragma unroll
    for (int i = 0; i < 8; i++) {
      int e = i * 256 + tid;
      int row = e >> 5, u = e & 31;
      *(i32x4*)&xs[row][u * 4] = src[e];
    }
  }
  {
    const i32x4* src = (const i32x4*)(wp + ((size_t)mat * DDIM + n0) * KPACK);
    #pragma unroll
    for (int i = 0; i < 8; i++) {
      int e = i * 256 + tid;
      int c = e >> 5, u = e & 31;
      *(i32x4*)&bs[c][u * 4] = src[e];
    }
  }
  if (tid < 64) sxs[tid] = sx[r0g + tid];
  __syncthreads();

  i32x4 acc[4];
  #pragma unroll
  for (int rt = 0; rt < 4; rt++) acc[rt] = (i32x4)(0);

  #pragma unroll
  for (int s = 0; s < 8; s++) {
    i32x4 bf = *(const i32x4*)&bs[w * 16 + col][s * 16 + quad * 4];
    #pragma unroll
    for (int rt = 0; rt < 4; rt++) {
      i32x4 af = *(const i32x4*)&xs[rt * 16 + col][s * 16 + quad * 4];
      acc[rt] = __builtin_amdgcn_mfma_i32_16x16x64_i8(af, bf, acc[rt], 0, 0, 0);
    }
  }

  const float mval = fmaxf(mw[mat] * (1.0f / 262144.0f), EPSQ);
  const int nw = n0 + w * 16 + col;     // this lane's output column

  if (mat < 2) {
    _Float16* outb = qkv + (size_t)mat * NROW * DDIM;
    #pragma unroll
    for (int rt = 0; rt < 4; rt++) {
      #pragma unroll
      for (int reg = 0; reg < 4; reg++) {
        int rowl = rt * 16 + quad * 4 + reg;
        outb[(size_t)(r0g + rowl) * DDIM + nw] =
            (_Float16)((float)acc[rt][reg] * sxs[rowl] * mval);
      }
    }
  } else {
    _Float16* vT = qkv + (size_t)2 * NROW * DDIM;
    #pragma unroll
    for (int rt = 0; rt < 4; rt++) {
      half4 hv;
      #pragma unroll
      for (int reg = 0; reg < 4; reg++) {
        int rowl = rt * 16 + quad * 4 + reg;
        hv[reg] = (_Float16)((float)acc[rt][reg] * sxs[rowl] * mval);
      }
      int r = r0g + rt * 16 + quad * 4;          // first of 4 consecutive keys
      int b = r >> 11, kt = (r & 2047) >> 5, kin = r & 31;
      *(half4*)(vT + ((((size_t)b * 64 + kt) * 512 + nw) * 32 + kin)) = hv;
    }
  }
}

// ---------------------------------------------------------------------------
// 5. f16 MFMA flash attention, split-K with STATIC complementary pairing.
//    Grid (32,8), block 512. Block (qi,b) runs slot (qt=qi,h=0) then slot
//    (qt=31-qi,h=1): (qi+1)+(32-qi) = 33 tiles per block, uniform. Every one
//    of the 512 slots computed exactly once (no duplication). Slot h takes
//    key-tiles h, h+2, ... of unit qt. Inner tile code identical to r8-r10
//    (bench-verified). Partials (unnormalized O, m, l) -> workspace.
// ---------------------------------------------------------------------------
__global__ __launch_bounds__(512, 2) void flash_kernel(
    const _Float16* __restrict__ q, const _Float16* __restrict__ k,
    const _Float16* __restrict__ vT, float* __restrict__ po,
    float* __restrict__ pm, float* __restrict__ pl) {
  __shared__ __align__(16) _Float16 Ksh[2][32][520];  // DMA rows
  __shared__ __align__(16) _Float16 VtL[2][512][32];  // DMA, swizzled
  __shared__ __align__(16) float    PsS[64 * 33];     // raw scores
  __shared__ __align__(16) _Float16 Pf[64 * 40];      // probabilities
  __shared__ float alpha_l[64];

  const int tid  = threadIdx.x;
  const int w    = tid >> 6;        // 0..7
  const int lane = tid & 63;
  const int quad = lane >> 4;
  const int col  = lane & 15;
  const int rt   = w & 3;           // score row-tile
  const int kh   = w >> 2;          // score key-half
  const int smrow = tid >> 3;       // softmax row 0..63
  const int sme   = tid & 7;        // softmax key group 0..7
  const int d0  = w * 64;           // PV dim slice

  const int vrl = lane >> 2;        // V-DMA row-in-group 0..15
  const int vu  = lane & 3;         // V-DMA 16B unit 0..3

  const int qi = blockIdx.x;        // 0..31
  const int bb = blockIdx.y;        // 0..7

  for (int ph = 0; ph < 2; ph++) {
    const int qt = ph ? (31 - qi) : qi;
    const int h  = ph;              // key-tile parity
    const int slot = ((qt * 8 + bb) * 2 + h);
    const int nT = qt + 1;          // tiles in this slot

    const int qrow0 = qt * 64;
    const size_t bbase = (size_t)bb * SEQ * DDIM;
    const _Float16* kb_p = k + bbase;
    const _Float16* vt_p = vT + (size_t)bb * 64 * 512 * 32;  // [kt][dim][key]

    half8 qfrag[16];
    {
      const _Float16* qrow_p = q + bbase + (size_t)(qrow0 + rt * 16 + col) * DDIM;
      #pragma unroll
      for (int s = 0; s < 16; s++)
        qfrag[s] = *(const half8*)(qrow_p + s * 32 + quad * 8);
    }

    float m_run = -INFINITY, l_run = 0.f;
    f32x4 o[4][4];
    #pragma unroll
    for (int a = 0; a < 4; a++)
      #pragma unroll
      for (int b2 = 0; b2 < 4; b2++) o[a][b2] = (f32x4)(0.f);

    // prologue: DMA K tile h + V tile h into buf 0
    #pragma unroll
    for (int i = 0; i < 4; i++)
      gld_lds16(kb_p + (size_t)(h * 32 + w * 4 + i) * DDIM + lane * 8,
                &Ksh[0][w * 4 + i][0]);
    {
      const _Float16* vtile = vt_p + (size_t)h * 512 * 32;
      #pragma unroll
      for (int i = 0; i < 4; i++) {
        int r = w * 64 + i * 16 + vrl;
        int su = vu ^ ((r >> 1) & 3);
        gld_lds16(vtile + (size_t)r * 32 + su * 8, &VtL[0][w * 64 + i * 16][0]);
      }
    }
    __syncthreads();

    for (int t = 0; t < nT; t++) {
      const int cur = t & 1, nxt = cur ^ 1;
      const int kb0 = (2 * t + h) * 32;

      // prefetch this slot's next tile (stride 2) — drains at barrier B
      if (t + 1 < nT) {
        const int kb1 = kb0 + 64;
        #pragma unroll
        for (int i = 0; i < 4; i++)
          gld_lds16(kb_p + (size_t)(kb1 + w * 4 + i) * DDIM + lane * 8,
                    &Ksh[nxt][w * 4 + i][0]);
        const _Float16* vtile = vt_p + (size_t)(2 * t + h + 2) * 512 * 32;
        #pragma unroll
        for (int i = 0; i < 4; i++) {
          int r = w * 64 + i * 16 + vrl;
          int su = vu ^ ((r >> 1) & 3);
          gld_lds16(vtile + (size_t)r * 32 + su * 8, &VtL[nxt][w * 64 + i * 16][0]);
        }
      }

      // ---- scores ----
      {
        f32x4 c = (f32x4)(0.f);
        #pragma unroll
        for (int s = 0; s < 16; s++) {
          half8 b = *(const half8*)&Ksh[cur][kh * 16 + col][s * 32 + quad * 8];
          c = __builtin_amdgcn_mfma_f32_16x16x32_f16(qfrag[s], b, c, 0, 0, 0);
        }
        #pragma unroll
        for (int reg = 0; reg < 4; reg++)
          PsS[(rt * 16 + quad * 4 + reg) * 33 + kh * 16 + col] = c[reg];
      }
      __syncthreads();   // B: scores ready (drains DMA prefetch)

      // ---- softmax ----
      {
        const int qrow = qrow0 + smrow;
        float sv[4];
        #pragma unroll
        for (int i = 0; i < 4; i++) {
          float s = PsS[smrow * 33 + sme * 4 + i] * FSCALE;
          if (kb0 + sme * 4 + i > qrow) s = -INFINITY;
          sv[i] = s;
        }
        float mx = fmaxf(fmaxf(sv[0], sv[1]), fmaxf(sv[2], sv[3]));
        #pragma unroll
        for (int m = 1; m <= 4; m <<= 1) mx = fmaxf(mx, __shfl_xor(mx, m, 64));
        float mn = fmaxf(m_run, mx);
        float mnc = fmaxf(mn, -1e30f);     // guard fully-masked rows
        float al = __expf(m_run - mnc);
        half4 p4;
        float rs = 0.f;
        #pragma unroll
        for (int i = 0; i < 4; i++) {
          float p = __expf(sv[i] - mnc);
          rs += p;
          p4[i] = (_Float16)p;
        }
        #pragma unroll
        for (int m = 1; m <= 4; m <<= 1) rs += __shfl_xor(rs, m, 64);
        l_run = l_run * al + rs;
        m_run = mn;
        *(half4*)&Pf[smrow * 40 + sme * 4] = p4;
        if (sme == 0) alpha_l[smrow] = al;
      }
      __syncthreads();   // C: Pf + alpha ready

      // ---- PV ----
      {
        half8 ap[4];
        f32x4 af[4];
        #pragma unroll
        for (int r2 = 0; r2 < 4; r2++) {
          ap[r2] = *(const half8*)&Pf[(r2 * 16 + col) * 40 + quad * 8];
          af[r2] = *(const f32x4*)&alpha_l[r2 * 16 + quad * 4];
        }
        #pragma unroll
        for (int r2 = 0; r2 < 4; r2++)
          #pragma unroll
          for (int ct = 0; ct < 4; ct++)
            o[r2][ct] *= af[r2];
        #pragma unroll
        for (int ct = 0; ct < 4; ct++) {
          int R = d0 + ct * 16 + col;
          int ur = quad ^ ((R >> 1) & 3);
          half8 bv = *(const half8*)&VtL[cur][R][ur * 8];
          #pragma unroll
          for (int r2 = 0; r2 < 4; r2++)
            o[r2][ct] = __builtin_amdgcn_mfma_f32_16x16x32_f16(ap[r2], bv, o[r2][ct], 0, 0, 0);
        }
      }
      __syncthreads();   // D: PV done; cur bufs may be re-DMA'd next iter
      // (barrier D also guarantees all LDS reads done before next phase's DMA)
    }

    // ---- epilogue: write unnormalized partials + m/l (global only) ----
    if (sme == 0) {
      pm[slot * 64 + smrow] = m_run;
      pl[slot * 64 + smrow] = l_run;
    }
    {
      float* pob = po + (size_t)slot * 64 * 512;
      #pragma unroll
      for (int r2 = 0; r2 < 4; r2++) {
        #pragma unroll
        for (int ct = 0; ct < 4; ct++) {
          #pragma unroll
          for (int e = 0; e < 4; e++) {
            pob[(size_t)(r2 * 16 + quad * 4 + e) * 512 + d0 + ct * 16 + col] =
                o[r2][ct][e];
          }
        }
      }
    }
  }
}

// ---------------------------------------------------------------------------
// 6. split-K merge: out = (w0*o0 + w1*o1) / (w0*l0 + w1*l1). grid (32,8).
//    (unchanged from r10 — bench-verified)
// ---------------------------------------------------------------------------
__global__ __launch_bounds__(256) void merge_kernel(
    const float* __restrict__ po, const float* __restrict__ pm,
    const float* __restrict__ pl, float* __restrict__ out) {
  __shared__ float w0s[64], w1s[64], dns[64];
  const int tid = threadIdx.x;
  const int qt = blockIdx.x, b = blockIdx.y;
  const int slot0 = (qt * 8 + b) * 2;
  const int slot1 = slot0 + 1;

  if (tid < 64) {
    float m0 = pm[slot0 * 64 + tid], m1 = pm[slot1 * 64 + tid];
    float l0 = pl[slot0 * 64 + tid], l1 = pl[slot1 * 64 + tid];
    float ms = fmaxf(m0, m1);                 // finite: slot0 has diagonal keys
    float a0 = __expf(m0 - ms);               // exp(-inf - finite) = 0 ok
    float a1 = __expf(m1 - ms);
    w0s[tid] = a0;
    w1s[tid] = a1;
    dns[tid] = 1.0f / (a0 * l0 + a1 * l1);
  }
  __syncthreads();

  const f32x4* p0 = (const f32x4*)(po + (size_t)slot0 * 64 * 512);
  const f32x4* p1 = (const f32x4*)(po + (size_t)slot1 * 64 * 512);
  f32x4* op = (f32x4*)(out + ((size_t)b * SEQ + qt * 64) * 512);
  #pragma unroll 4
  for (int j = 0; j < 32; j++) {
    int e = j * 256 + tid;          // f32x4 units, row-major 64x128
    int row = e >> 7;
    f32x4 r = (p0[e] * w0s[row] + p1[e] * w1s[row]) * dns[row];
    op[e] = r;
  }
}

// ---------------------------------------------------------------------------
extern "C" void kernel_launch(void* const* d_in, const int* in_sizes, int n_in,
                              void* d_out, int out_size, void* d_ws, size_t ws_size,
                              hipStream_t stream) {
  const float* x  = (const float*)d_in[0];
  const float* Wq = (const float*)d_in[1];
  const float* Wk = (const float*)d_in[2];
  const float* Wv = (const float*)d_in[3];
  float* out = (float*)d_out;
  char* ws = (char*)d_ws;

  float* mw  = (float*)(ws + OFF_M);
  int*   wp  = (int*)(ws + OFF_WP);
  int*   xq  = (int*)(ws + OFF_XQ);
  float* sx  = (float*)(ws + OFF_SX);
  _Float16* qkv = (_Float16*)(ws + OFF_QKV);
  _Float16* qf  = qkv;
  _Float16* kf  = qkv + (size_t)NROW * DDIM;
  _Float16* vTf = qkv + 2 * (size_t)NROW * DDIM;
  float* po = (float*)(ws + OFF_PO);
  float* pm = (float*)(ws + OFF_PM);
  float* pl = (float*)(ws + OFF_PL);

  hipMemsetAsync(mw, 0, 16, stream);
  wsum_kernel<<<dim3(32, 3), 256, 0, stream>>>(Wq, Wk, Wv, mw);
  wquant_kernel<<<768, 256, 0, stream>>>(Wq, Wk, Wv, mw, wp);
  aquant_kernel<<<4096, 256, 0, stream>>>(x, xq, sx);
  qkv_gemm_kernel<<<dim3(256, 8, 3), 256, 0, stream>>>(xq, wp, sx, mw, qkv);
  flash_kernel<<<dim3(32, 8), 512, 0, stream>>>(qf, kf, vTf, po, pm, pl);
  merge_kernel<<<dim3(32, 8), 256, 0, stream>>>(po, pm, pl, out);
}